// Round 3
// baseline (1207.360 us; speedup 1.0000x reference)
//
#include <hip/hip_runtime.h>
#include <cfloat>

static __device__ __forceinline__ float lrelu(float v) { return v >= 0.f ? v : 0.2f * v; }

// ---------------- GEMM: C[M,N] = A[M,K] @ B[K,N] (+bias) (+relu) ----------------
// 128x128 tile, 256 threads, 8x8 per thread. Requires N%128==0, K%16==0.
// M guarded (works for M=64 MLP tiles and M=13120).
__global__ __launch_bounds__(256, 4) void gemm_k(const float* __restrict__ A,
                                                 const float* __restrict__ B,
                                                 const float* __restrict__ bias,
                                                 float* __restrict__ C,
                                                 int M, int K, int N, int relu)
{
    __shared__ float As[16][132];   // transposed: As[k][row]
    __shared__ float Bs[16][132];   // Bs[k][col]
    const int tid = threadIdx.x;
    const int tr = tid >> 4, tc = tid & 15;
    const int row0 = blockIdx.x * 128, col0 = blockIdx.y * 128;

    // staging map: A rows r=tid>>1, k-halves h=tid&1 -> k offsets h*4, h*4+8
    const int sr = tid >> 1;
    const int sh = (tid & 1) * 4;
    // B rows brow=tid>>4, col chunk (tid&15)*8
    const int brow = tid >> 4;
    const int bc = (tid & 15) * 8;

    float4 acc[8][2];
#pragma unroll
    for (int i = 0; i < 8; i++) { acc[i][0] = make_float4(0,0,0,0); acc[i][1] = make_float4(0,0,0,0); }

    const float4 zero4 = make_float4(0, 0, 0, 0);
    for (int k0 = 0; k0 < K; k0 += 16) {
        bool aok = (row0 + sr) < M;
        float4 a0 = aok ? *reinterpret_cast<const float4*>(&A[(size_t)(row0 + sr) * K + k0 + sh])     : zero4;
        float4 a1 = aok ? *reinterpret_cast<const float4*>(&A[(size_t)(row0 + sr) * K + k0 + sh + 8]) : zero4;
        float4 b0 = *reinterpret_cast<const float4*>(&B[(size_t)(k0 + brow) * N + col0 + bc]);
        float4 b1 = *reinterpret_cast<const float4*>(&B[(size_t)(k0 + brow) * N + col0 + bc + 4]);
        __syncthreads();
        As[sh + 0][sr] = a0.x; As[sh + 1][sr] = a0.y; As[sh + 2][sr] = a0.z; As[sh + 3][sr] = a0.w;
        As[sh + 8][sr] = a1.x; As[sh + 9][sr] = a1.y; As[sh +10][sr] = a1.z; As[sh +11][sr] = a1.w;
        *reinterpret_cast<float4*>(&Bs[brow][bc])     = b0;
        *reinterpret_cast<float4*>(&Bs[brow][bc + 4]) = b1;
        __syncthreads();
#pragma unroll
        for (int kk = 0; kk < 16; kk++) {
            float4 aL = *reinterpret_cast<const float4*>(&As[kk][tr * 4]);
            float4 aH = *reinterpret_cast<const float4*>(&As[kk][64 + tr * 4]);
            float4 bL = *reinterpret_cast<const float4*>(&Bs[kk][tc * 4]);
            float4 bH = *reinterpret_cast<const float4*>(&Bs[kk][64 + tc * 4]);
            float av[8] = {aL.x, aL.y, aL.z, aL.w, aH.x, aH.y, aH.z, aH.w};
#pragma unroll
            for (int i = 0; i < 8; i++) {
                acc[i][0].x += av[i] * bL.x; acc[i][0].y += av[i] * bL.y;
                acc[i][0].z += av[i] * bL.z; acc[i][0].w += av[i] * bL.w;
                acc[i][1].x += av[i] * bH.x; acc[i][1].y += av[i] * bH.y;
                acc[i][1].z += av[i] * bH.z; acc[i][1].w += av[i] * bH.w;
            }
        }
    }
#pragma unroll
    for (int i = 0; i < 8; i++) {
        int rr = row0 + ((i < 4) ? (tr * 4 + i) : (64 + tr * 4 + (i - 4)));
        if (rr < M) {
#pragma unroll
            for (int j = 0; j < 2; j++) {
                int cc = col0 + (j ? (64 + tc * 4) : (tc * 4));
                float4 v = acc[i][j];
                if (bias) {
                    float4 bb = *reinterpret_cast<const float4*>(&bias[cc]);
                    v.x += bb.x; v.y += bb.y; v.z += bb.z; v.w += bb.w;
                }
                if (relu) {
                    v.x = fmaxf(v.x, 0.f); v.y = fmaxf(v.y, 0.f);
                    v.z = fmaxf(v.z, 0.f); v.w = fmaxf(v.w, 0.f);
                }
                *reinterpret_cast<float4*>(&C[(size_t)rr * N + cc]) = v;
            }
        }
    }
}

// ---------------- per-(node,head) attention coefficients e_src, e_dst ----------------
__global__ __launch_bounds__(256) void escd_k(const float* __restrict__ H,
                                              const float* __restrict__ a_src,
                                              const float* __restrict__ a_dst,
                                              float* __restrict__ es, float* __restrict__ ed, int n)
{
    int wid = (int)((blockIdx.x * 256 + threadIdx.x) >> 6);
    int lane = threadIdx.x & 63;
    if (wid >= n * 3) return;
    int node = wid / 3, head = wid - node * 3;
    const float* hp = H + (size_t)node * 384 + head * 128;
    const float* aps = a_src + head * 128;
    const float* apd = a_dst + head * 128;
    float h0 = hp[lane], h1 = hp[lane + 64];
    float s = h0 * aps[lane] + h1 * aps[lane + 64];
    float d = h0 * apd[lane] + h1 * apd[lane + 64];
#pragma unroll
    for (int o = 32; o > 0; o >>= 1) { s += __shfl_down(s, o); d += __shfl_down(d, o); }
    if (lane == 0) { es[wid] = s; ed[wid] = d; }
}

// ---------------- CSR build ----------------
__global__ __launch_bounds__(256) void count_k(const int* __restrict__ dst,
                                               const int* __restrict__ valid,
                                               int* __restrict__ deg, int E)
{
    int e = blockIdx.x * 256 + threadIdx.x;
    if (e >= E) return;
    if (!valid || valid[e]) atomicAdd(&deg[dst[e]], 1);
}

__global__ __launch_bounds__(1024) void scan_k(const int* __restrict__ deg,
                                               int* __restrict__ off, int* __restrict__ cur, int n)
{
    __shared__ int part[1024];
    int t = threadIdx.x;
    int chunk = (n + 1023) >> 10;
    int b0 = t * chunk;
    int b1 = min(n, b0 + chunk);
    int s = 0;
    for (int i = b0; i < b1; i++) s += deg[i];
    part[t] = s;
    __syncthreads();
    for (int d = 1; d < 1024; d <<= 1) {
        int v = (t >= d) ? part[t - d] : 0;
        __syncthreads();
        part[t] += v;
        __syncthreads();
    }
    int excl = (t ? part[t - 1] : 0);
    for (int i = b0; i < b1; i++) { off[i] = excl; cur[i] = excl; excl += deg[i]; }
    if (t == 1023) off[n] = part[1023];
}

__global__ __launch_bounds__(256) void scatter_k(const int* __restrict__ dst,
                                                 const int* __restrict__ valid,
                                                 int* __restrict__ cur, int* __restrict__ csr, int E)
{
    int e = blockIdx.x * 256 + threadIdx.x;
    if (e >= E) return;
    if (!valid || valid[e]) {
        int p = atomicAdd(&cur[dst[e]], 1);
        csr[p] = e;
    }
}

// ---------------- per-dst max / denominator / self-weight (one THREAD per dst) ----------------
__global__ __launch_bounds__(256) void maxden_k(const float* __restrict__ es,
                                                const float* __restrict__ ed,
                                                const int* __restrict__ roff,
                                                const int* __restrict__ csr,
                                                const int* __restrict__ srcArr,
                                                float* __restrict__ wmx,
                                                float* __restrict__ winv,
                                                float* __restrict__ wself, int n)
{
    int d = blockIdx.x * 256 + threadIdx.x;
    if (d >= n) return;
    float edv[3], selfl[3], mx[3];
#pragma unroll
    for (int h = 0; h < 3; h++) {
        edv[h] = ed[(size_t)d * 3 + h];
        selfl[h] = lrelu(es[(size_t)d * 3 + h] + edv[h]);
        mx[h] = selfl[h];
    }
    const int beg = roff[d], end = roff[d + 1];
    for (int e = beg; e < end; e++) {
        int s = srcArr[csr[e]];
#pragma unroll
        for (int h = 0; h < 3; h++) mx[h] = fmaxf(mx[h], lrelu(es[(size_t)s * 3 + h] + edv[h]));
    }
    float den[3];
#pragma unroll
    for (int h = 0; h < 3; h++) den[h] = __expf(selfl[h] - mx[h]);
    for (int e = beg; e < end; e++) {
        int s = srcArr[csr[e]];
#pragma unroll
        for (int h = 0; h < 3; h++) den[h] += __expf(lrelu(es[(size_t)s * 3 + h] + edv[h]) - mx[h]);
    }
#pragma unroll
    for (int h = 0; h < 3; h++) {
        float inv = 1.f / (den[h] + 1e-16f);
        wmx[(size_t)d * 3 + h] = mx[h];
        winv[(size_t)d * 3 + h] = inv;
        wself[(size_t)d * 3 + h] = __expf(selfl[h] - mx[h]) * inv;
    }
}

// ---------------- per-edge alpha (one thread per edge) ----------------
__global__ __launch_bounds__(256) void alpha_k(const int* __restrict__ src,
                                               const int* __restrict__ dst,
                                               const int* __restrict__ valid,
                                               const float* __restrict__ es,
                                               const float* __restrict__ ed,
                                               const float* __restrict__ wmx,
                                               const float* __restrict__ winv,
                                               float* __restrict__ alpha, int E)
{
    int e = blockIdx.x * 256 + threadIdx.x;
    if (e >= E) return;
    if (valid && !valid[e]) return;
    int s = src[e], d = dst[e];
#pragma unroll
    for (int h = 0; h < 3; h++) {
        float l = lrelu(es[(size_t)s * 3 + h] + ed[(size_t)d * 3 + h]);
        alpha[(size_t)e * 3 + h] = __expf(l - wmx[(size_t)d * 3 + h]) * winv[(size_t)d * 3 + h];
    }
}

// ---------------- alpha-weighted gather (one wave per dst, XCD-swizzled) ----------------
__global__ __launch_bounds__(256) void agg2_k(const float* __restrict__ H,
                                              const float* __restrict__ alpha,
                                              const float* __restrict__ wself,
                                              const int* __restrict__ roff,
                                              const int* __restrict__ csr,
                                              const int* __restrict__ srcArr,
                                              const float* __restrict__ bias,
                                              float* __restrict__ out, int n)
{
    // XCD-aware swizzle: contiguous chunks of blocks per XCD (gridDim.x % 8 == 0)
    int nwg = gridDim.x;
    int bid = blockIdx.x;
    int swz = (bid & 7) * (nwg >> 3) + (bid >> 3);
    int wid = swz * 4 + (int)(threadIdx.x >> 6);
    int lane = threadIdx.x & 63;
    if (wid >= n) return;
    const int d = wid;
    float wsf[3];
#pragma unroll
    for (int h = 0; h < 3; h++) wsf[h] = wself[(size_t)d * 3 + h];
    float acc[6];
    const float* hp = H + (size_t)d * 384;
#pragma unroll
    for (int j = 0; j < 6; j++) acc[j] = wsf[j >> 1] * hp[lane + 64 * j];
    const int beg = roff[d], end = roff[d + 1];
    for (int e = beg; e < end; e++) {
        int ce = csr[e];
        int s = srcArr[ce];
        float a0 = alpha[(size_t)ce * 3 + 0];
        float a1 = alpha[(size_t)ce * 3 + 1];
        float a2 = alpha[(size_t)ce * 3 + 2];
        const float* sp = H + (size_t)s * 384;
        acc[0] += a0 * sp[lane];
        acc[1] += a0 * sp[lane + 64];
        acc[2] += a1 * sp[lane + 128];
        acc[3] += a1 * sp[lane + 192];
        acc[4] += a2 * sp[lane + 256];
        acc[5] += a2 * sp[lane + 320];
    }
#pragma unroll
    for (int j = 0; j < 6; j++)
        out[(size_t)d * 384 + lane + 64 * j] = acc[j] + bias[lane + 64 * j];
}

// ---------------- TopK pooling score: tanh(x.w / ||w||)  (one wave per node) ----------------
__global__ __launch_bounds__(256) void score_k(const float* __restrict__ H,
                                               const float* __restrict__ w,
                                               float* __restrict__ sc, int n)
{
    int wid = (int)((blockIdx.x * 256 + threadIdx.x) >> 6);
    int lane = threadIdx.x & 63;
    if (wid >= n) return;
    float w0 = w[lane], w1 = w[lane + 64];
    const float* hp = H + (size_t)wid * 128;
    float s = hp[lane] * w0 + hp[lane + 64] * w1;
    float q = w0 * w0 + w1 * w1;
#pragma unroll
    for (int o = 32; o > 0; o >>= 1) { s += __shfl_down(s, o); q += __shfl_down(q, o); }
    if (lane == 0) sc[wid] = tanhf(s / sqrtf(q));
}

// ---------------- per-graph top-k selection (bitonic sort, desc score, asc idx tiebreak) ----------------
__global__ __launch_bounds__(512) void select_k(const float* __restrict__ sc,
                                                int per, int k,
                                                int* __restrict__ perm, float* __restrict__ ps,
                                                int* __restrict__ newid)
{
    __shared__ float s[512];
    __shared__ int id[512];
    const int b = blockIdx.x;
    const int t = threadIdx.x;
    const int P = blockDim.x;
    if (t < per) { s[t] = sc[(size_t)b * per + t]; id[t] = t; }
    else         { s[t] = -FLT_MAX; id[t] = per + t; }
    __syncthreads();
    for (int kk = 2; kk <= P; kk <<= 1)
        for (int j = kk >> 1; j > 0; j >>= 1) {
            int ixj = t ^ j;
            if (ixj > t) {
                float a = s[t], bq = s[ixj];
                int ia = id[t], ib = id[ixj];
                bool aBefore = (a > bq) || (a == bq && ia < ib);
                bool up = ((t & kk) == 0);
                if (up ? !aBefore : aBefore) { s[t] = bq; s[ixj] = a; id[t] = ib; id[ixj] = ia; }
            }
            __syncthreads();
        }
    if (t < k) {
        int og = b * per + id[t];
        int ng = b * k + t;
        perm[ng] = og;
        ps[ng] = s[t];
        newid[og] = ng;
    }
}

// ---------------- gated copy of kept nodes (one wave per new node) ----------------
__global__ __launch_bounds__(256) void gate_k(const float* __restrict__ H,
                                              const int* __restrict__ perm,
                                              const float* __restrict__ ps,
                                              float* __restrict__ X, int nNew)
{
    int wid = (int)((blockIdx.x * 256 + threadIdx.x) >> 6);
    int lane = threadIdx.x & 63;
    if (wid >= nNew) return;
    int o = perm[wid];
    float g = ps[wid];
    X[(size_t)wid * 128 + lane]      = H[(size_t)o * 128 + lane] * g;
    X[(size_t)wid * 128 + 64 + lane] = H[(size_t)o * 128 + 64 + lane] * g;
}

// ---------------- edge remap through pooling ----------------
__global__ __launch_bounds__(256) void remap_k(const int* __restrict__ s_old,
                                               const int* __restrict__ d_old,
                                               const int* __restrict__ v_old,
                                               const int* __restrict__ newid,
                                               int* __restrict__ s_new, int* __restrict__ d_new,
                                               int* __restrict__ v_new, int E)
{
    int e = blockIdx.x * 256 + threadIdx.x;
    if (e >= E) return;
    int v = v_old ? v_old[e] : 1;
    int ns = -1, nd = -1;
    if (v) { ns = newid[s_old[e]]; nd = newid[d_old[e]]; }
    int ok = (v && ns >= 0 && nd >= 0) ? 1 : 0;
    s_new[e] = ok ? ns : 0;
    d_new[e] = ok ? nd : 0;
    v_new[e] = ok;
}

// ---------------- global max+mean pool, accumulated into z ----------------
__global__ __launch_bounds__(1024) void gpool_k(const float* __restrict__ X,
                                                float* __restrict__ z, int k)
{
    __shared__ float smx[8][128];
    __shared__ float ssm[8][128];
    const int b = blockIdx.x;
    const int col = threadIdx.x & 127;
    const int rg = threadIdx.x >> 7;
    const float* xp = X + (size_t)b * k * 128 + col;
    float mx = -FLT_MAX, sm = 0.f;
    int r = rg;
#pragma unroll 4
    for (; r + 32 <= k; r += 32) {
        float v0 = xp[(size_t)(r + 0)  * 128];
        float v1 = xp[(size_t)(r + 8)  * 128];
        float v2 = xp[(size_t)(r + 16) * 128];
        float v3 = xp[(size_t)(r + 24) * 128];
        mx = fmaxf(fmaxf(fmaxf(mx, v0), fmaxf(v1, v2)), v3);
        sm += v0 + v1 + v2 + v3;
    }
    for (; r < k; r += 8) {
        float v = xp[(size_t)r * 128];
        mx = fmaxf(mx, v);
        sm += v;
    }
    smx[rg][col] = mx;
    ssm[rg][col] = sm;
    __syncthreads();
    if (rg == 0) {
#pragma unroll
        for (int i = 1; i < 8; i++) { mx = fmaxf(mx, smx[i][col]); sm += ssm[i][col]; }
        z[b * 256 + col] += mx;
        z[b * 256 + 128 + col] += sm / (float)k;
    }
}

extern "C" void kernel_launch(void* const* d_in, const int* in_sizes, int n_in,
                              void* d_out, int out_size, void* d_ws, size_t ws_size,
                              hipStream_t stream)
{
    (void)in_sizes; (void)n_in; (void)out_size; (void)ws_size;

    const float* x   = (const float*)d_in[0];
    const int*   ei  = (const int*)d_in[2];
    const float* W1  = (const float*)d_in[4];
    const float* as1 = (const float*)d_in[5];
    const float* ad1 = (const float*)d_in[6];
    const float* b1  = (const float*)d_in[7];
    const float* Wh1 = (const float*)d_in[8];
    const float* bh1 = (const float*)d_in[9];
    const float* pw1 = (const float*)d_in[10];
    const float* W2  = (const float*)d_in[11];
    const float* as2 = (const float*)d_in[12];
    const float* ad2 = (const float*)d_in[13];
    const float* b2  = (const float*)d_in[14];
    const float* Wh2 = (const float*)d_in[15];
    const float* bh2 = (const float*)d_in[16];
    const float* pw2 = (const float*)d_in[17];
    const float* W3  = (const float*)d_in[18];
    const float* as3 = (const float*)d_in[19];
    const float* ad3 = (const float*)d_in[20];
    const float* b3  = (const float*)d_in[21];
    const float* Wh3 = (const float*)d_in[22];
    const float* bh3 = (const float*)d_in[23];
    const float* pw3 = (const float*)d_in[24];
    const float* Wl1 = (const float*)d_in[25];
    const float* bl1 = (const float*)d_in[26];
    const float* Wl2 = (const float*)d_in[27];
    const float* bl2 = (const float*)d_in[28];
    float* out = (float*)d_out;

    const int E = 131072;
    const int n1 = 32768, per1 = 512, k1 = 410;
    const int n2 = 64 * k1, per2 = k1, k2 = 205;   // 26240, 410, 205
    const int n3 = 64 * k2, per3 = k2, k3 = 41;    // 13120, 205, 41
    const int n4 = 64 * k3;                        // 2624

    // ---- workspace carve ----
    char* wsb = (char*)d_ws;
    size_t off = 0;
    auto alloc = [&](size_t bytes) -> void* {
        void* p = wsb + off;
        off += (bytes + 255) & ~(size_t)255;
        return p;
    };
    float* A    = (float*)alloc((size_t)n1 * 384 * 4);  // h_lin, later h2
    float* Bf   = (float*)alloc((size_t)n1 * 384 * 4);  // gat output
    float* ES   = (float*)alloc((size_t)n1 * 3 * 4);
    float* ED   = (float*)alloc((size_t)n1 * 3 * 4);
    float* SC   = (float*)alloc((size_t)n1 * 4);
    int*   DEG  = (int*)alloc((size_t)(n1 + 1) * 4);
    int*   OFFS = (int*)alloc((size_t)(n1 + 1) * 4);
    int*   CUR  = (int*)alloc((size_t)n1 * 4);
    int*   CSR  = (int*)alloc((size_t)E * 4);
    int*   SRCA = (int*)alloc((size_t)E * 4);
    int*   DSTA = (int*)alloc((size_t)E * 4);
    int*   VALA = (int*)alloc((size_t)E * 4);
    int*   SRCB = (int*)alloc((size_t)E * 4);
    int*   DSTB = (int*)alloc((size_t)E * 4);
    int*   VALB = (int*)alloc((size_t)E * 4);
    float* X1   = (float*)alloc((size_t)n2 * 128 * 4);
    float* X2   = (float*)alloc((size_t)n3 * 128 * 4);
    float* X3   = (float*)alloc((size_t)n4 * 128 * 4);
    int*   PERM = (int*)alloc((size_t)n2 * 4);
    float* PSC  = (float*)alloc((size_t)n2 * 4);
    int*   NEWID= (int*)alloc((size_t)n1 * 4);
    float* WMX  = (float*)alloc((size_t)n1 * 3 * 4);
    float* WINV = (float*)alloc((size_t)n1 * 3 * 4);
    float* WSELF= (float*)alloc((size_t)n1 * 3 * 4);
    float* ALPHA= (float*)alloc((size_t)E * 3 * 4);
    float* Z    = (float*)alloc((size_t)64 * 256 * 4);
    float* ZH   = (float*)alloc((size_t)64 * 512 * 4);

    auto layer = [&](const float* xin, int n,
                     const int* src, const int* dst, const int* val,
                     const float* W, const float* as_, const float* ad_, const float* bb,
                     const float* Wh, const float* bh, const float* pw,
                     int per, int kk, float* Xn, int nNew,
                     int* srcN, int* dstN, int* valN)
    {
        gemm_k<<<dim3((n + 127) / 128, 384 / 128), 256, 0, stream>>>(xin, W, nullptr, A, n, 128, 384, 0);
        escd_k<<<(n * 3) / 4, 256, 0, stream>>>(A, as_, ad_, ES, ED, n);
        hipMemsetAsync(DEG, 0, (size_t)n * 4, stream);
        count_k<<<E / 256, 256, 0, stream>>>(dst, val, DEG, E);
        scan_k<<<1, 1024, 0, stream>>>(DEG, OFFS, CUR, n);
        scatter_k<<<E / 256, 256, 0, stream>>>(dst, val, CUR, CSR, E);
        maxden_k<<<(n + 255) / 256, 256, 0, stream>>>(ES, ED, OFFS, CSR, src, WMX, WINV, WSELF, n);
        alpha_k<<<E / 256, 256, 0, stream>>>(src, dst, val, ES, ED, WMX, WINV, ALPHA, E);
        agg2_k<<<n / 4, 256, 0, stream>>>(A, ALPHA, WSELF, OFFS, CSR, src, bb, Bf, n);
        gemm_k<<<dim3((n + 127) / 128, 128 / 128), 256, 0, stream>>>(Bf, Wh, bh, A, n, 384, 128, 1);
        score_k<<<n / 4, 256, 0, stream>>>(A, pw, SC, n);
        hipMemsetAsync(NEWID, 0xFF, (size_t)n * 4, stream);
        int P2 = 1;
        while (P2 < per) P2 <<= 1;
        select_k<<<64, P2, 0, stream>>>(SC, per, kk, PERM, PSC, NEWID);
        gate_k<<<nNew / 4, 256, 0, stream>>>(A, PERM, PSC, Xn, nNew);
        if (srcN) remap_k<<<E / 256, 256, 0, stream>>>(src, dst, val, NEWID, srcN, dstN, valN, E);
        gpool_k<<<64, 1024, 0, stream>>>(Xn, Z, kk);
    };

    hipMemsetAsync(Z, 0, (size_t)64 * 256 * 4, stream);

    layer(x,  n1, ei,   ei + E, nullptr, W1, as1, ad1, b1, Wh1, bh1, pw1, per1, k1, X1, n2, SRCA, DSTA, VALA);
    layer(X1, n2, SRCA, DSTA,   VALA,    W2, as2, ad2, b2, Wh2, bh2, pw2, per2, k2, X2, n3, SRCB, DSTB, VALB);
    layer(X2, n3, SRCB, DSTB,   VALB,    W3, as3, ad3, b3, Wh3, bh3, pw3, per3, k3, X3, n4, nullptr, nullptr, nullptr);

    gemm_k<<<dim3(1, 512 / 128), 256, 0, stream>>>(Z,  Wl1, bl1, ZH,  64, 256, 512, 1);
    gemm_k<<<dim3(1, 256 / 128), 256, 0, stream>>>(ZH, Wl2, bl2, out, 64, 512, 256, 0);
}

// Round 4
// 777.297 us; speedup vs baseline: 1.5533x; 1.5533x over previous
//
#include <hip/hip_runtime.h>
#include <cfloat>

static __device__ __forceinline__ float lrelu(float v) { return v >= 0.f ? v : 0.2f * v; }

// ---------------- GEMM: C[M,N] = A[M,K] @ B[K,N] (+bias) (+relu) ----------------
// 128x128 tile, 256 threads, 8x8 per thread. Requires N%128==0, K%16==0.
// M guarded. launch_bounds(256,2): VGPR cap 256 so the 64-reg accumulator
// stays in VGPRs (round-3 lesson: (256,4) forced VGPR=64 -> spilled acc).
__global__ __launch_bounds__(256, 2) void gemm_k(const float* __restrict__ A,
                                                 const float* __restrict__ B,
                                                 const float* __restrict__ bias,
                                                 float* __restrict__ C,
                                                 int M, int K, int N, int relu)
{
    __shared__ float As[16][132];   // transposed: As[k][row]
    __shared__ float Bs[16][132];   // Bs[k][col]
    const int tid = threadIdx.x;
    const int tr = tid >> 4, tc = tid & 15;
    const int row0 = blockIdx.x * 128, col0 = blockIdx.y * 128;

    const int sr = tid >> 1;
    const int sh = (tid & 1) * 4;
    const int brow = tid >> 4;
    const int bc = (tid & 15) * 8;

    float4 acc[8][2];
#pragma unroll
    for (int i = 0; i < 8; i++) { acc[i][0] = make_float4(0,0,0,0); acc[i][1] = make_float4(0,0,0,0); }

    const float4 zero4 = make_float4(0, 0, 0, 0);
    for (int k0 = 0; k0 < K; k0 += 16) {
        bool aok = (row0 + sr) < M;
        float4 a0 = aok ? *reinterpret_cast<const float4*>(&A[(size_t)(row0 + sr) * K + k0 + sh])     : zero4;
        float4 a1 = aok ? *reinterpret_cast<const float4*>(&A[(size_t)(row0 + sr) * K + k0 + sh + 8]) : zero4;
        float4 b0 = *reinterpret_cast<const float4*>(&B[(size_t)(k0 + brow) * N + col0 + bc]);
        float4 b1 = *reinterpret_cast<const float4*>(&B[(size_t)(k0 + brow) * N + col0 + bc + 4]);
        __syncthreads();
        As[sh + 0][sr] = a0.x; As[sh + 1][sr] = a0.y; As[sh + 2][sr] = a0.z; As[sh + 3][sr] = a0.w;
        As[sh + 8][sr] = a1.x; As[sh + 9][sr] = a1.y; As[sh +10][sr] = a1.z; As[sh +11][sr] = a1.w;
        *reinterpret_cast<float4*>(&Bs[brow][bc])     = b0;
        *reinterpret_cast<float4*>(&Bs[brow][bc + 4]) = b1;
        __syncthreads();
#pragma unroll
        for (int kk = 0; kk < 16; kk++) {
            float4 aL = *reinterpret_cast<const float4*>(&As[kk][tr * 4]);
            float4 aH = *reinterpret_cast<const float4*>(&As[kk][64 + tr * 4]);
            float4 bL = *reinterpret_cast<const float4*>(&Bs[kk][tc * 4]);
            float4 bH = *reinterpret_cast<const float4*>(&Bs[kk][64 + tc * 4]);
            float av[8] = {aL.x, aL.y, aL.z, aL.w, aH.x, aH.y, aH.z, aH.w};
#pragma unroll
            for (int i = 0; i < 8; i++) {
                acc[i][0].x += av[i] * bL.x; acc[i][0].y += av[i] * bL.y;
                acc[i][0].z += av[i] * bL.z; acc[i][0].w += av[i] * bL.w;
                acc[i][1].x += av[i] * bH.x; acc[i][1].y += av[i] * bH.y;
                acc[i][1].z += av[i] * bH.z; acc[i][1].w += av[i] * bH.w;
            }
        }
    }
#pragma unroll
    for (int i = 0; i < 8; i++) {
        int rr = row0 + ((i < 4) ? (tr * 4 + i) : (64 + tr * 4 + (i - 4)));
        if (rr < M) {
#pragma unroll
            for (int j = 0; j < 2; j++) {
                int cc = col0 + (j ? (64 + tc * 4) : (tc * 4));
                float4 v = acc[i][j];
                if (bias) {
                    float4 bb = *reinterpret_cast<const float4*>(&bias[cc]);
                    v.x += bb.x; v.y += bb.y; v.z += bb.z; v.w += bb.w;
                }
                if (relu) {
                    v.x = fmaxf(v.x, 0.f); v.y = fmaxf(v.y, 0.f);
                    v.z = fmaxf(v.z, 0.f); v.w = fmaxf(v.w, 0.f);
                }
                *reinterpret_cast<float4*>(&C[(size_t)rr * N + cc]) = v;
            }
        }
    }
}

// ---------------- small-M GEMM (MLP head, M=64): one thread per output ----------------
__global__ __launch_bounds__(256) void gemm_small_k(const float* __restrict__ A,
                                                    const float* __restrict__ B,
                                                    const float* __restrict__ bias,
                                                    float* __restrict__ C,
                                                    int M, int K, int N, int relu)
{
    int idx = blockIdx.x * 256 + threadIdx.x;
    if (idx >= M * N) return;
    int r = idx / N, c = idx - r * N;
    const float* ap = A + (size_t)r * K;
    const float* bp = B + c;
    float s = 0.f;
#pragma unroll 8
    for (int k = 0; k < K; k++) s += ap[k] * bp[(size_t)k * N];
    if (bias) s += bias[c];
    if (relu) s = fmaxf(s, 0.f);
    C[idx] = s;
}

// ---------------- per-(node,head) attention coefficients e_src, e_dst ----------------
__global__ __launch_bounds__(256) void escd_k(const float* __restrict__ H,
                                              const float* __restrict__ a_src,
                                              const float* __restrict__ a_dst,
                                              float* __restrict__ es, float* __restrict__ ed, int n)
{
    int wid = (int)((blockIdx.x * 256 + threadIdx.x) >> 6);
    int lane = threadIdx.x & 63;
    if (wid >= n * 3) return;
    int node = wid / 3, head = wid - node * 3;
    const float* hp = H + (size_t)node * 384 + head * 128;
    const float* aps = a_src + head * 128;
    const float* apd = a_dst + head * 128;
    float h0 = hp[lane], h1 = hp[lane + 64];
    float s = h0 * aps[lane] + h1 * aps[lane + 64];
    float d = h0 * apd[lane] + h1 * apd[lane + 64];
#pragma unroll
    for (int o = 32; o > 0; o >>= 1) { s += __shfl_down(s, o); d += __shfl_down(d, o); }
    if (lane == 0) { es[wid] = s; ed[wid] = d; }
}

// ---------------- CSR build ----------------
__global__ __launch_bounds__(256) void count_k(const int* __restrict__ dst,
                                               const int* __restrict__ valid,
                                               int* __restrict__ deg, int E)
{
    int e = blockIdx.x * 256 + threadIdx.x;
    if (e >= E) return;
    if (!valid || valid[e]) atomicAdd(&deg[dst[e]], 1);
}

__global__ __launch_bounds__(1024) void scan_k(const int* __restrict__ deg,
                                               int* __restrict__ off, int* __restrict__ cur, int n)
{
    __shared__ int part[1024];
    int t = threadIdx.x;
    int chunk = (n + 1023) >> 10;
    int b0 = t * chunk;
    int b1 = min(n, b0 + chunk);
    int s = 0;
    for (int i = b0; i < b1; i++) s += deg[i];
    part[t] = s;
    __syncthreads();
    for (int d = 1; d < 1024; d <<= 1) {
        int v = (t >= d) ? part[t - d] : 0;
        __syncthreads();
        part[t] += v;
        __syncthreads();
    }
    int excl = (t ? part[t - 1] : 0);
    for (int i = b0; i < b1; i++) { off[i] = excl; cur[i] = excl; excl += deg[i]; }
    if (t == 1023) off[n] = part[1023];
}

__global__ __launch_bounds__(256) void scatter_k(const int* __restrict__ dst,
                                                 const int* __restrict__ valid,
                                                 int* __restrict__ cur, int* __restrict__ csr, int E)
{
    int e = blockIdx.x * 256 + threadIdx.x;
    if (e >= E) return;
    if (!valid || valid[e]) {
        int p = atomicAdd(&cur[dst[e]], 1);
        csr[p] = e;
    }
}

// ---------------- per-dst max / denominator / self-weight (one THREAD per dst) ----------------
__global__ __launch_bounds__(256) void maxden_k(const float* __restrict__ es,
                                                const float* __restrict__ ed,
                                                const int* __restrict__ roff,
                                                const int* __restrict__ csr,
                                                const int* __restrict__ srcArr,
                                                float* __restrict__ wmx,
                                                float* __restrict__ winv,
                                                float* __restrict__ wself, int n)
{
    int d = blockIdx.x * 256 + threadIdx.x;
    if (d >= n) return;
    float edv[3], selfl[3], mx[3];
#pragma unroll
    for (int h = 0; h < 3; h++) {
        edv[h] = ed[(size_t)d * 3 + h];
        selfl[h] = lrelu(es[(size_t)d * 3 + h] + edv[h]);
        mx[h] = selfl[h];
    }
    const int beg = roff[d], end = roff[d + 1];
    for (int e = beg; e < end; e++) {
        int s = srcArr[csr[e]];
#pragma unroll
        for (int h = 0; h < 3; h++) mx[h] = fmaxf(mx[h], lrelu(es[(size_t)s * 3 + h] + edv[h]));
    }
    float den[3];
#pragma unroll
    for (int h = 0; h < 3; h++) den[h] = __expf(selfl[h] - mx[h]);
    for (int e = beg; e < end; e++) {
        int s = srcArr[csr[e]];
#pragma unroll
        for (int h = 0; h < 3; h++) den[h] += __expf(lrelu(es[(size_t)s * 3 + h] + edv[h]) - mx[h]);
    }
#pragma unroll
    for (int h = 0; h < 3; h++) {
        float inv = 1.f / (den[h] + 1e-16f);
        wmx[(size_t)d * 3 + h] = mx[h];
        winv[(size_t)d * 3 + h] = inv;
        wself[(size_t)d * 3 + h] = __expf(selfl[h] - mx[h]) * inv;
    }
}

// ---------------- per-edge alpha (one thread per edge) ----------------
__global__ __launch_bounds__(256) void alpha_k(const int* __restrict__ src,
                                               const int* __restrict__ dst,
                                               const int* __restrict__ valid,
                                               const float* __restrict__ es,
                                               const float* __restrict__ ed,
                                               const float* __restrict__ wmx,
                                               const float* __restrict__ winv,
                                               float* __restrict__ alpha, int E)
{
    int e = blockIdx.x * 256 + threadIdx.x;
    if (e >= E) return;
    if (valid && !valid[e]) return;
    int s = src[e], d = dst[e];
#pragma unroll
    for (int h = 0; h < 3; h++) {
        float l = lrelu(es[(size_t)s * 3 + h] + ed[(size_t)d * 3 + h]);
        alpha[(size_t)e * 3 + h] = __expf(l - wmx[(size_t)d * 3 + h]) * winv[(size_t)d * 3 + h];
    }
}

// ---------------- alpha-weighted gather (one wave per dst, XCD-swizzled) ----------------
__global__ __launch_bounds__(256) void agg2_k(const float* __restrict__ H,
                                              const float* __restrict__ alpha,
                                              const float* __restrict__ wself,
                                              const int* __restrict__ roff,
                                              const int* __restrict__ csr,
                                              const int* __restrict__ srcArr,
                                              const float* __restrict__ bias,
                                              float* __restrict__ out, int n)
{
    int nwg = gridDim.x;
    int bid = blockIdx.x;
    int swz = (bid & 7) * (nwg >> 3) + (bid >> 3);
    int wid = swz * 4 + (int)(threadIdx.x >> 6);
    int lane = threadIdx.x & 63;
    if (wid >= n) return;
    const int d = wid;
    float wsf[3];
#pragma unroll
    for (int h = 0; h < 3; h++) wsf[h] = wself[(size_t)d * 3 + h];
    float acc[6];
    const float* hp = H + (size_t)d * 384;
#pragma unroll
    for (int j = 0; j < 6; j++) acc[j] = wsf[j >> 1] * hp[lane + 64 * j];
    const int beg = roff[d], end = roff[d + 1];
    for (int e = beg; e < end; e++) {
        int ce = csr[e];
        int s = srcArr[ce];
        float a0 = alpha[(size_t)ce * 3 + 0];
        float a1 = alpha[(size_t)ce * 3 + 1];
        float a2 = alpha[(size_t)ce * 3 + 2];
        const float* sp = H + (size_t)s * 384;
        acc[0] += a0 * sp[lane];
        acc[1] += a0 * sp[lane + 64];
        acc[2] += a1 * sp[lane + 128];
        acc[3] += a1 * sp[lane + 192];
        acc[4] += a2 * sp[lane + 256];
        acc[5] += a2 * sp[lane + 320];
    }
#pragma unroll
    for (int j = 0; j < 6; j++)
        out[(size_t)d * 384 + lane + 64 * j] = acc[j] + bias[lane + 64 * j];
}

// ---------------- TopK pooling score: tanh(x.w / ||w||)  (one wave per node) ----------------
__global__ __launch_bounds__(256) void score_k(const float* __restrict__ H,
                                               const float* __restrict__ w,
                                               float* __restrict__ sc, int n)
{
    int wid = (int)((blockIdx.x * 256 + threadIdx.x) >> 6);
    int lane = threadIdx.x & 63;
    if (wid >= n) return;
    float w0 = w[lane], w1 = w[lane + 64];
    const float* hp = H + (size_t)wid * 128;
    float s = hp[lane] * w0 + hp[lane + 64] * w1;
    float q = w0 * w0 + w1 * w1;
#pragma unroll
    for (int o = 32; o > 0; o >>= 1) { s += __shfl_down(s, o); q += __shfl_down(q, o); }
    if (lane == 0) sc[wid] = tanhf(s / sqrtf(q));
}

// ---------------- per-graph top-k selection (bitonic sort, desc score, asc idx tiebreak) ----------------
__global__ __launch_bounds__(512) void select_k(const float* __restrict__ sc,
                                                int per, int k,
                                                int* __restrict__ perm, float* __restrict__ ps,
                                                int* __restrict__ newid)
{
    __shared__ float s[512];
    __shared__ int id[512];
    const int b = blockIdx.x;
    const int t = threadIdx.x;
    const int P = blockDim.x;
    if (t < per) { s[t] = sc[(size_t)b * per + t]; id[t] = t; }
    else         { s[t] = -FLT_MAX; id[t] = per + t; }
    __syncthreads();
    for (int kk = 2; kk <= P; kk <<= 1)
        for (int j = kk >> 1; j > 0; j >>= 1) {
            int ixj = t ^ j;
            if (ixj > t) {
                float a = s[t], bq = s[ixj];
                int ia = id[t], ib = id[ixj];
                bool aBefore = (a > bq) || (a == bq && ia < ib);
                bool up = ((t & kk) == 0);
                if (up ? !aBefore : aBefore) { s[t] = bq; s[ixj] = a; id[t] = ib; id[ixj] = ia; }
            }
            __syncthreads();
        }
    if (t < k) {
        int og = b * per + id[t];
        int ng = b * k + t;
        perm[ng] = og;
        ps[ng] = s[t];
        newid[og] = ng;
    }
}

// ---------------- gated copy of kept nodes (one wave per new node) ----------------
__global__ __launch_bounds__(256) void gate_k(const float* __restrict__ H,
                                              const int* __restrict__ perm,
                                              const float* __restrict__ ps,
                                              float* __restrict__ X, int nNew)
{
    int wid = (int)((blockIdx.x * 256 + threadIdx.x) >> 6);
    int lane = threadIdx.x & 63;
    if (wid >= nNew) return;
    int o = perm[wid];
    float g = ps[wid];
    X[(size_t)wid * 128 + lane]      = H[(size_t)o * 128 + lane] * g;
    X[(size_t)wid * 128 + 64 + lane] = H[(size_t)o * 128 + 64 + lane] * g;
}

// ---------------- edge remap through pooling ----------------
__global__ __launch_bounds__(256) void remap_k(const int* __restrict__ s_old,
                                               const int* __restrict__ d_old,
                                               const int* __restrict__ v_old,
                                               const int* __restrict__ newid,
                                               int* __restrict__ s_new, int* __restrict__ d_new,
                                               int* __restrict__ v_new, int E)
{
    int e = blockIdx.x * 256 + threadIdx.x;
    if (e >= E) return;
    int v = v_old ? v_old[e] : 1;
    int ns = -1, nd = -1;
    if (v) { ns = newid[s_old[e]]; nd = newid[d_old[e]]; }
    int ok = (v && ns >= 0 && nd >= 0) ? 1 : 0;
    s_new[e] = ok ? ns : 0;
    d_new[e] = ok ? nd : 0;
    v_new[e] = ok;
}

// ---------------- global max+mean pool, accumulated into z ----------------
__global__ __launch_bounds__(1024) void gpool_k(const float* __restrict__ X,
                                                float* __restrict__ z, int k)
{
    __shared__ float smx[8][128];
    __shared__ float ssm[8][128];
    const int b = blockIdx.x;
    const int col = threadIdx.x & 127;
    const int rg = threadIdx.x >> 7;
    const float* xp = X + (size_t)b * k * 128 + col;
    float mx = -FLT_MAX, sm = 0.f;
    int r = rg;
#pragma unroll 4
    for (; r + 32 <= k; r += 32) {
        float v0 = xp[(size_t)(r + 0)  * 128];
        float v1 = xp[(size_t)(r + 8)  * 128];
        float v2 = xp[(size_t)(r + 16) * 128];
        float v3 = xp[(size_t)(r + 24) * 128];
        mx = fmaxf(fmaxf(fmaxf(mx, v0), fmaxf(v1, v2)), v3);
        sm += v0 + v1 + v2 + v3;
    }
    for (; r < k; r += 8) {
        float v = xp[(size_t)r * 128];
        mx = fmaxf(mx, v);
        sm += v;
    }
    smx[rg][col] = mx;
    ssm[rg][col] = sm;
    __syncthreads();
    if (rg == 0) {
#pragma unroll
        for (int i = 1; i < 8; i++) { mx = fmaxf(mx, smx[i][col]); sm += ssm[i][col]; }
        z[b * 256 + col] += mx;
        z[b * 256 + 128 + col] += sm / (float)k;
    }
}

extern "C" void kernel_launch(void* const* d_in, const int* in_sizes, int n_in,
                              void* d_out, int out_size, void* d_ws, size_t ws_size,
                              hipStream_t stream)
{
    (void)in_sizes; (void)n_in; (void)out_size; (void)ws_size;

    const float* x   = (const float*)d_in[0];
    const int*   ei  = (const int*)d_in[2];
    const float* W1  = (const float*)d_in[4];
    const float* as1 = (const float*)d_in[5];
    const float* ad1 = (const float*)d_in[6];
    const float* b1  = (const float*)d_in[7];
    const float* Wh1 = (const float*)d_in[8];
    const float* bh1 = (const float*)d_in[9];
    const float* pw1 = (const float*)d_in[10];
    const float* W2  = (const float*)d_in[11];
    const float* as2 = (const float*)d_in[12];
    const float* ad2 = (const float*)d_in[13];
    const float* b2  = (const float*)d_in[14];
    const float* Wh2 = (const float*)d_in[15];
    const float* bh2 = (const float*)d_in[16];
    const float* pw2 = (const float*)d_in[17];
    const float* W3  = (const float*)d_in[18];
    const float* as3 = (const float*)d_in[19];
    const float* ad3 = (const float*)d_in[20];
    const float* b3  = (const float*)d_in[21];
    const float* Wh3 = (const float*)d_in[22];
    const float* bh3 = (const float*)d_in[23];
    const float* pw3 = (const float*)d_in[24];
    const float* Wl1 = (const float*)d_in[25];
    const float* bl1 = (const float*)d_in[26];
    const float* Wl2 = (const float*)d_in[27];
    const float* bl2 = (const float*)d_in[28];
    float* out = (float*)d_out;

    const int E = 131072;
    const int n1 = 32768, per1 = 512, k1 = 410;
    const int n2 = 64 * k1, per2 = k1, k2 = 205;   // 26240, 410, 205
    const int n3 = 64 * k2, per3 = k2, k3 = 41;    // 13120, 205, 41
    const int n4 = 64 * k3;                        // 2624

    // ---- workspace carve ----
    char* wsb = (char*)d_ws;
    size_t off = 0;
    auto alloc = [&](size_t bytes) -> void* {
        void* p = wsb + off;
        off += (bytes + 255) & ~(size_t)255;
        return p;
    };
    float* A    = (float*)alloc((size_t)n1 * 384 * 4);  // h_lin, later h2
    float* Bf   = (float*)alloc((size_t)n1 * 384 * 4);  // gat output
    float* ES   = (float*)alloc((size_t)n1 * 3 * 4);
    float* ED   = (float*)alloc((size_t)n1 * 3 * 4);
    float* SC   = (float*)alloc((size_t)n1 * 4);
    int*   DEG  = (int*)alloc((size_t)(n1 + 1) * 4);
    int*   OFFS = (int*)alloc((size_t)(n1 + 1) * 4);
    int*   CUR  = (int*)alloc((size_t)n1 * 4);
    int*   CSR  = (int*)alloc((size_t)E * 4);
    int*   SRCA = (int*)alloc((size_t)E * 4);
    int*   DSTA = (int*)alloc((size_t)E * 4);
    int*   VALA = (int*)alloc((size_t)E * 4);
    int*   SRCB = (int*)alloc((size_t)E * 4);
    int*   DSTB = (int*)alloc((size_t)E * 4);
    int*   VALB = (int*)alloc((size_t)E * 4);
    float* X1   = (float*)alloc((size_t)n2 * 128 * 4);
    float* X2   = (float*)alloc((size_t)n3 * 128 * 4);
    float* X3   = (float*)alloc((size_t)n4 * 128 * 4);
    int*   PERM = (int*)alloc((size_t)n2 * 4);
    float* PSC  = (float*)alloc((size_t)n2 * 4);
    int*   NEWID= (int*)alloc((size_t)n1 * 4);
    float* WMX  = (float*)alloc((size_t)n1 * 3 * 4);
    float* WINV = (float*)alloc((size_t)n1 * 3 * 4);
    float* WSELF= (float*)alloc((size_t)n1 * 3 * 4);
    float* ALPHA= (float*)alloc((size_t)E * 3 * 4);
    float* Z    = (float*)alloc((size_t)64 * 256 * 4);
    float* ZH   = (float*)alloc((size_t)64 * 512 * 4);

    auto layer = [&](const float* xin, int n,
                     const int* src, const int* dst, const int* val,
                     const float* W, const float* as_, const float* ad_, const float* bb,
                     const float* Wh, const float* bh, const float* pw,
                     int per, int kk, float* Xn, int nNew,
                     int* srcN, int* dstN, int* valN)
    {
        gemm_k<<<dim3((n + 127) / 128, 384 / 128), 256, 0, stream>>>(xin, W, nullptr, A, n, 128, 384, 0);
        escd_k<<<(n * 3) / 4, 256, 0, stream>>>(A, as_, ad_, ES, ED, n);
        hipMemsetAsync(DEG, 0, (size_t)n * 4, stream);
        count_k<<<E / 256, 256, 0, stream>>>(dst, val, DEG, E);
        scan_k<<<1, 1024, 0, stream>>>(DEG, OFFS, CUR, n);
        scatter_k<<<E / 256, 256, 0, stream>>>(dst, val, CUR, CSR, E);
        maxden_k<<<(n + 255) / 256, 256, 0, stream>>>(ES, ED, OFFS, CSR, src, WMX, WINV, WSELF, n);
        alpha_k<<<E / 256, 256, 0, stream>>>(src, dst, val, ES, ED, WMX, WINV, ALPHA, E);
        agg2_k<<<n / 4, 256, 0, stream>>>(A, ALPHA, WSELF, OFFS, CSR, src, bb, Bf, n);
        gemm_k<<<dim3((n + 127) / 128, 128 / 128), 256, 0, stream>>>(Bf, Wh, bh, A, n, 384, 128, 1);
        score_k<<<n / 4, 256, 0, stream>>>(A, pw, SC, n);
        hipMemsetAsync(NEWID, 0xFF, (size_t)n * 4, stream);
        int P2 = 1;
        while (P2 < per) P2 <<= 1;
        select_k<<<64, P2, 0, stream>>>(SC, per, kk, PERM, PSC, NEWID);
        gate_k<<<nNew / 4, 256, 0, stream>>>(A, PERM, PSC, Xn, nNew);
        if (srcN) remap_k<<<E / 256, 256, 0, stream>>>(src, dst, val, NEWID, srcN, dstN, valN, E);
        gpool_k<<<64, 1024, 0, stream>>>(Xn, Z, kk);
    };

    hipMemsetAsync(Z, 0, (size_t)64 * 256 * 4, stream);

    layer(x,  n1, ei,   ei + E, nullptr, W1, as1, ad1, b1, Wh1, bh1, pw1, per1, k1, X1, n2, SRCA, DSTA, VALA);
    layer(X1, n2, SRCA, DSTA,   VALA,    W2, as2, ad2, b2, Wh2, bh2, pw2, per2, k2, X2, n3, SRCB, DSTB, VALB);
    layer(X2, n3, SRCB, DSTB,   VALB,    W3, as3, ad3, b3, Wh3, bh3, pw3, per3, k3, X3, n4, nullptr, nullptr, nullptr);

    gemm_small_k<<<(64 * 512 + 255) / 256, 256, 0, stream>>>(Z,  Wl1, bl1, ZH,  64, 256, 512, 1);
    gemm_small_k<<<(64 * 256 + 255) / 256, 256, 0, stream>>>(ZH, Wl2, bl2, out, 64, 512, 256, 0);
}

// Round 5
// 592.264 us; speedup vs baseline: 2.0386x; 1.3124x over previous
//
#include <hip/hip_runtime.h>
#include <cfloat>

static __device__ __forceinline__ float lrelu(float v) { return v >= 0.f ? v : 0.2f * v; }

typedef __attribute__((ext_vector_type(8))) short bf16x8;
typedef __attribute__((ext_vector_type(4))) float f32x4;

__device__ __forceinline__ unsigned short f2bf(float x) {
    unsigned u = __float_as_uint(x);
    u += 0x7FFF + ((u >> 16) & 1);          // RNE to bf16
    return (unsigned short)(u >> 16);
}
__device__ __forceinline__ float bf2f(unsigned short h) {
    return __uint_as_float(((unsigned)h) << 16);
}

// ---------------- MFMA GEMM, fp32 in/out, split-bf16 (3-term Ootomo) ----------------
// C[M,N] = A[M,K] @ B[K,N] (+bias)(+relu). Requires K%32==0, N%128==0; M guarded.
// 128x128 tile, 256 thr = 4 waves (2x2 of 64x64), BK=32.
// LDS tiles hold bf16 hi/lo with 16B-chunk XOR swizzle: chunk ^= (r ^ (r>>2)) & 3.
__global__ __launch_bounds__(256) void gemm_mfma_k(const float* __restrict__ A,
                                                   const float* __restrict__ B,
                                                   const float* __restrict__ bias,
                                                   float* __restrict__ C,
                                                   int M, int K, int N, int relu)
{
    __shared__ unsigned short AsH[128 * 32], AsL[128 * 32];   // [row][k] bf16
    __shared__ unsigned short BsH[128 * 32], BsL[128 * 32];   // [col][k] bf16 (transposed)
    const int tid  = threadIdx.x;
    const int lane = tid & 63;
    const int wave = tid >> 6;
    const int wr = (wave >> 1) * 64;
    const int wc = (wave & 1) * 64;
    const int row0 = blockIdx.x * 128, col0 = blockIdx.y * 128;

    f32x4 acc[4][4];
#pragma unroll
    for (int i = 0; i < 4; i++)
#pragma unroll
        for (int j = 0; j < 4; j++) acc[i][j] = (f32x4){0.f, 0.f, 0.f, 0.f};

    // staging maps
    const int ar  = tid >> 1;            // A row 0..127
    const int afb = (tid & 1) * 4;       // A float4 index base (0 or 4)
    const int bk  = tid & 31;            // B k-row 0..31
    const int bnb = (tid >> 5) * 16;     // B col base (0..112)

    const int l15 = lane & 15;
    const int kc  = lane >> 4;           // k-chunk 0..3

    const bool aok = (row0 + ar) < M;

    for (int k0 = 0; k0 < K; k0 += 32) {
        float4 av[4], bv[4];
        const float* Ap = A + (size_t)(row0 + ar) * K + k0;
        const float* Bp = B + (size_t)(k0 + bk) * N + col0 + bnb;
#pragma unroll
        for (int i = 0; i < 4; i++)
            av[i] = aok ? *reinterpret_cast<const float4*>(Ap + (afb + i) * 4)
                        : make_float4(0.f, 0.f, 0.f, 0.f);
#pragma unroll
        for (int i = 0; i < 4; i++)
            bv[i] = *reinterpret_cast<const float4*>(Bp + i * 4);

        __syncthreads();   // previous iteration's LDS reads done

        // ---- stage A (hi/lo, swizzled, packed uint writes) ----
        const int asz = (ar ^ (ar >> 2)) & 3;
#pragma unroll
        for (int i = 0; i < 4; i++) {
            int f = afb + i;
            int uidx = ar * 16 + (((f >> 1) ^ asz) << 2) + (f & 1) * 2;
            float xs[4] = {av[i].x, av[i].y, av[i].z, av[i].w};
            unsigned short h[4], l[4];
#pragma unroll
            for (int j = 0; j < 4; j++) {
                h[j] = f2bf(xs[j]);
                l[j] = f2bf(xs[j] - bf2f(h[j]));
            }
            ((unsigned*)AsH)[uidx]     = (unsigned)h[0] | ((unsigned)h[1] << 16);
            ((unsigned*)AsH)[uidx + 1] = (unsigned)h[2] | ((unsigned)h[3] << 16);
            ((unsigned*)AsL)[uidx]     = (unsigned)l[0] | ((unsigned)l[1] << 16);
            ((unsigned*)AsL)[uidx + 1] = (unsigned)l[2] | ((unsigned)l[3] << 16);
        }
        // ---- stage B transposed (hi/lo, swizzled, scalar ushort writes) ----
#pragma unroll
        for (int i = 0; i < 4; i++) {
            float xs[4] = {bv[i].x, bv[i].y, bv[i].z, bv[i].w};
#pragma unroll
            for (int j = 0; j < 4; j++) {
                int c = bnb + i * 4 + j;
                int sidx = c * 32 + ((((bk >> 3) ^ ((c ^ (c >> 2)) & 3))) << 3) + (bk & 7);
                unsigned short h = f2bf(xs[j]);
                BsH[sidx] = h;
                BsL[sidx] = f2bf(xs[j] - bf2f(h));
            }
        }
        __syncthreads();

        // ---- fragments ----
        bf16x8 aH[4], aL[4], bH[4], bL[4];
#pragma unroll
        for (int fi = 0; fi < 4; fi++) {
            int r = wr + fi * 16 + l15;
            int sidx = r * 32 + ((kc ^ ((r ^ (r >> 2)) & 3)) << 3);
            aH[fi] = *reinterpret_cast<const bf16x8*>(&AsH[sidx]);
            aL[fi] = *reinterpret_cast<const bf16x8*>(&AsL[sidx]);
        }
#pragma unroll
        for (int fj = 0; fj < 4; fj++) {
            int c = wc + fj * 16 + l15;
            int sidx = c * 32 + ((kc ^ ((c ^ (c >> 2)) & 3)) << 3);
            bH[fj] = *reinterpret_cast<const bf16x8*>(&BsH[sidx]);
            bL[fj] = *reinterpret_cast<const bf16x8*>(&BsL[sidx]);
        }
        // ---- 3-term MFMA ----
#pragma unroll
        for (int fi = 0; fi < 4; fi++)
#pragma unroll
            for (int fj = 0; fj < 4; fj++) {
                acc[fi][fj] = __builtin_amdgcn_mfma_f32_16x16x32_bf16(aH[fi], bH[fj], acc[fi][fj], 0, 0, 0);
                acc[fi][fj] = __builtin_amdgcn_mfma_f32_16x16x32_bf16(aH[fi], bL[fj], acc[fi][fj], 0, 0, 0);
                acc[fi][fj] = __builtin_amdgcn_mfma_f32_16x16x32_bf16(aL[fi], bH[fj], acc[fi][fj], 0, 0, 0);
            }
    }

    // ---- epilogue: C/D layout col=lane&15, row=(lane>>4)*4+q ----
#pragma unroll
    for (int fi = 0; fi < 4; fi++) {
        int rbase = row0 + wr + fi * 16 + (lane >> 4) * 4;
#pragma unroll
        for (int q = 0; q < 4; q++) {
            int r = rbase + q;
            if (r < M) {
#pragma unroll
                for (int fj = 0; fj < 4; fj++) {
                    int c = col0 + wc + fj * 16 + l15;
                    float v = acc[fi][fj][q];
                    if (bias) v += bias[c];
                    if (relu) v = fmaxf(v, 0.f);
                    C[(size_t)r * N + c] = v;
                }
            }
        }
    }
}

// ---------------- small-M GEMM (MLP head, M=64): one thread per output ----------------
__global__ __launch_bounds__(256) void gemm_small_k(const float* __restrict__ A,
                                                    const float* __restrict__ B,
                                                    const float* __restrict__ bias,
                                                    float* __restrict__ C,
                                                    int M, int K, int N, int relu)
{
    int idx = blockIdx.x * 256 + threadIdx.x;
    if (idx >= M * N) return;
    int r = idx / N, c = idx - r * N;
    const float* ap = A + (size_t)r * K;
    const float* bp = B + c;
    float s = 0.f;
#pragma unroll 8
    for (int k = 0; k < K; k++) s += ap[k] * bp[(size_t)k * N];
    if (bias) s += bias[c];
    if (relu) s = fmaxf(s, 0.f);
    C[idx] = s;
}

// ---------------- per-(node,head) attention coefficients e_src, e_dst ----------------
__global__ __launch_bounds__(256) void escd_k(const float* __restrict__ H,
                                              const float* __restrict__ a_src,
                                              const float* __restrict__ a_dst,
                                              float* __restrict__ es, float* __restrict__ ed, int n)
{
    int wid = (int)((blockIdx.x * 256 + threadIdx.x) >> 6);
    int lane = threadIdx.x & 63;
    if (wid >= n * 3) return;
    int node = wid / 3, head = wid - node * 3;
    const float* hp = H + (size_t)node * 384 + head * 128;
    const float* aps = a_src + head * 128;
    const float* apd = a_dst + head * 128;
    float h0 = hp[lane], h1 = hp[lane + 64];
    float s = h0 * aps[lane] + h1 * aps[lane + 64];
    float d = h0 * apd[lane] + h1 * apd[lane + 64];
#pragma unroll
    for (int o = 32; o > 0; o >>= 1) { s += __shfl_down(s, o); d += __shfl_down(d, o); }
    if (lane == 0) { es[wid] = s; ed[wid] = d; }
}

// ---------------- CSR build ----------------
__global__ __launch_bounds__(256) void count_k(const int* __restrict__ dst,
                                               const int* __restrict__ valid,
                                               int* __restrict__ deg, int E)
{
    int e = blockIdx.x * 256 + threadIdx.x;
    if (e >= E) return;
    if (!valid || valid[e]) atomicAdd(&deg[dst[e]], 1);
}

__global__ __launch_bounds__(1024) void scan_k(const int* __restrict__ deg,
                                               int* __restrict__ off, int* __restrict__ cur, int n)
{
    __shared__ int part[1024];
    int t = threadIdx.x;
    int chunk = (n + 1023) >> 10;
    int b0 = t * chunk;
    int b1 = min(n, b0 + chunk);
    int s = 0;
    for (int i = b0; i < b1; i++) s += deg[i];
    part[t] = s;
    __syncthreads();
    for (int d = 1; d < 1024; d <<= 1) {
        int v = (t >= d) ? part[t - d] : 0;
        __syncthreads();
        part[t] += v;
        __syncthreads();
    }
    int excl = (t ? part[t - 1] : 0);
    for (int i = b0; i < b1; i++) { off[i] = excl; cur[i] = excl; excl += deg[i]; }
    if (t == 1023) off[n] = part[1023];
}

__global__ __launch_bounds__(256) void scatter_k(const int* __restrict__ dst,
                                                 const int* __restrict__ valid,
                                                 int* __restrict__ cur, int* __restrict__ csr, int E)
{
    int e = blockIdx.x * 256 + threadIdx.x;
    if (e >= E) return;
    if (!valid || valid[e]) {
        int p = atomicAdd(&cur[dst[e]], 1);
        csr[p] = e;
    }
}

// ---------------- per-dst max / denominator / self-weight (one THREAD per dst) ----------------
__global__ __launch_bounds__(256) void maxden_k(const float* __restrict__ es,
                                                const float* __restrict__ ed,
                                                const int* __restrict__ roff,
                                                const int* __restrict__ csr,
                                                const int* __restrict__ srcArr,
                                                float* __restrict__ wmx,
                                                float* __restrict__ winv,
                                                float* __restrict__ wself, int n)
{
    int d = blockIdx.x * 256 + threadIdx.x;
    if (d >= n) return;
    float edv[3], selfl[3], mx[3];
#pragma unroll
    for (int h = 0; h < 3; h++) {
        edv[h] = ed[(size_t)d * 3 + h];
        selfl[h] = lrelu(es[(size_t)d * 3 + h] + edv[h]);
        mx[h] = selfl[h];
    }
    const int beg = roff[d], end = roff[d + 1];
    for (int e = beg; e < end; e++) {
        int s = srcArr[csr[e]];
#pragma unroll
        for (int h = 0; h < 3; h++) mx[h] = fmaxf(mx[h], lrelu(es[(size_t)s * 3 + h] + edv[h]));
    }
    float den[3];
#pragma unroll
    for (int h = 0; h < 3; h++) den[h] = __expf(selfl[h] - mx[h]);
    for (int e = beg; e < end; e++) {
        int s = srcArr[csr[e]];
#pragma unroll
        for (int h = 0; h < 3; h++) den[h] += __expf(lrelu(es[(size_t)s * 3 + h] + edv[h]) - mx[h]);
    }
#pragma unroll
    for (int h = 0; h < 3; h++) {
        float inv = 1.f / (den[h] + 1e-16f);
        wmx[(size_t)d * 3 + h] = mx[h];
        winv[(size_t)d * 3 + h] = inv;
        wself[(size_t)d * 3 + h] = __expf(selfl[h] - mx[h]) * inv;
    }
}

// ---------------- per-edge alpha (one thread per edge) ----------------
__global__ __launch_bounds__(256) void alpha_k(const int* __restrict__ src,
                                               const int* __restrict__ dst,
                                               const int* __restrict__ valid,
                                               const float* __restrict__ es,
                                               const float* __restrict__ ed,
                                               const float* __restrict__ wmx,
                                               const float* __restrict__ winv,
                                               float* __restrict__ alpha, int E)
{
    int e = blockIdx.x * 256 + threadIdx.x;
    if (e >= E) return;
    if (valid && !valid[e]) return;
    int s = src[e], d = dst[e];
#pragma unroll
    for (int h = 0; h < 3; h++) {
        float l = lrelu(es[(size_t)s * 3 + h] + ed[(size_t)d * 3 + h]);
        alpha[(size_t)e * 3 + h] = __expf(l - wmx[(size_t)d * 3 + h]) * winv[(size_t)d * 3 + h];
    }
}

// ---------------- alpha-weighted gather (one wave per dst, XCD-swizzled) ----------------
__global__ __launch_bounds__(256) void agg2_k(const float* __restrict__ H,
                                              const float* __restrict__ alpha,
                                              const float* __restrict__ wself,
                                              const int* __restrict__ roff,
                                              const int* __restrict__ csr,
                                              const int* __restrict__ srcArr,
                                              const float* __restrict__ bias,
                                              float* __restrict__ out, int n)
{
    int nwg = gridDim.x;
    int bid = blockIdx.x;
    int swz = (bid & 7) * (nwg >> 3) + (bid >> 3);
    int wid = swz * 4 + (int)(threadIdx.x >> 6);
    int lane = threadIdx.x & 63;
    if (wid >= n) return;
    const int d = wid;
    float wsf[3];
#pragma unroll
    for (int h = 0; h < 3; h++) wsf[h] = wself[(size_t)d * 3 + h];
    float acc[6];
    const float* hp = H + (size_t)d * 384;
#pragma unroll
    for (int j = 0; j < 6; j++) acc[j] = wsf[j >> 1] * hp[lane + 64 * j];
    const int beg = roff[d], end = roff[d + 1];
    for (int e = beg; e < end; e++) {
        int ce = csr[e];
        int s = srcArr[ce];
        float a0 = alpha[(size_t)ce * 3 + 0];
        float a1 = alpha[(size_t)ce * 3 + 1];
        float a2 = alpha[(size_t)ce * 3 + 2];
        const float* sp = H + (size_t)s * 384;
        acc[0] += a0 * sp[lane];
        acc[1] += a0 * sp[lane + 64];
        acc[2] += a1 * sp[lane + 128];
        acc[3] += a1 * sp[lane + 192];
        acc[4] += a2 * sp[lane + 256];
        acc[5] += a2 * sp[lane + 320];
    }
#pragma unroll
    for (int j = 0; j < 6; j++)
        out[(size_t)d * 384 + lane + 64 * j] = acc[j] + bias[lane + 64 * j];
}

// ---------------- TopK pooling score: tanh(x.w / ||w||)  (one wave per node) ----------------
__global__ __launch_bounds__(256) void score_k(const float* __restrict__ H,
                                               const float* __restrict__ w,
                                               float* __restrict__ sc, int n)
{
    int wid = (int)((blockIdx.x * 256 + threadIdx.x) >> 6);
    int lane = threadIdx.x & 63;
    if (wid >= n) return;
    float w0 = w[lane], w1 = w[lane + 64];
    const float* hp = H + (size_t)wid * 128;
    float s = hp[lane] * w0 + hp[lane + 64] * w1;
    float q = w0 * w0 + w1 * w1;
#pragma unroll
    for (int o = 32; o > 0; o >>= 1) { s += __shfl_down(s, o); q += __shfl_down(q, o); }
    if (lane == 0) sc[wid] = tanhf(s / sqrtf(q));
}

// ---------------- per-graph top-k selection (bitonic sort, desc score, asc idx tiebreak) ----------------
__global__ __launch_bounds__(512) void select_k(const float* __restrict__ sc,
                                                int per, int k,
                                                int* __restrict__ perm, float* __restrict__ ps,
                                                int* __restrict__ newid)
{
    __shared__ float s[512];
    __shared__ int id[512];
    const int b = blockIdx.x;
    const int t = threadIdx.x;
    const int P = blockDim.x;
    if (t < per) { s[t] = sc[(size_t)b * per + t]; id[t] = t; }
    else         { s[t] = -FLT_MAX; id[t] = per + t; }
    __syncthreads();
    for (int kk = 2; kk <= P; kk <<= 1)
        for (int j = kk >> 1; j > 0; j >>= 1) {
            int ixj = t ^ j;
            if (ixj > t) {
                float a = s[t], bq = s[ixj];
                int ia = id[t], ib = id[ixj];
                bool aBefore = (a > bq) || (a == bq && ia < ib);
                bool up = ((t & kk) == 0);
                if (up ? !aBefore : aBefore) { s[t] = bq; s[ixj] = a; id[t] = ib; id[ixj] = ia; }
            }
            __syncthreads();
        }
    if (t < k) {
        int og = b * per + id[t];
        int ng = b * k + t;
        perm[ng] = og;
        ps[ng] = s[t];
        newid[og] = ng;
    }
}

// ---------------- gated copy of kept nodes (one wave per new node) ----------------
__global__ __launch_bounds__(256) void gate_k(const float* __restrict__ H,
                                              const int* __restrict__ perm,
                                              const float* __restrict__ ps,
                                              float* __restrict__ X, int nNew)
{
    int wid = (int)((blockIdx.x * 256 + threadIdx.x) >> 6);
    int lane = threadIdx.x & 63;
    if (wid >= nNew) return;
    int o = perm[wid];
    float g = ps[wid];
    X[(size_t)wid * 128 + lane]      = H[(size_t)o * 128 + lane] * g;
    X[(size_t)wid * 128 + 64 + lane] = H[(size_t)o * 128 + 64 + lane] * g;
}

// ---------------- edge remap through pooling ----------------
__global__ __launch_bounds__(256) void remap_k(const int* __restrict__ s_old,
                                               const int* __restrict__ d_old,
                                               const int* __restrict__ v_old,
                                               const int* __restrict__ newid,
                                               int* __restrict__ s_new, int* __restrict__ d_new,
                                               int* __restrict__ v_new, int E)
{
    int e = blockIdx.x * 256 + threadIdx.x;
    if (e >= E) return;
    int v = v_old ? v_old[e] : 1;
    int ns = -1, nd = -1;
    if (v) { ns = newid[s_old[e]]; nd = newid[d_old[e]]; }
    int ok = (v && ns >= 0 && nd >= 0) ? 1 : 0;
    s_new[e] = ok ? ns : 0;
    d_new[e] = ok ? nd : 0;
    v_new[e] = ok;
}

// ---------------- global max+mean pool, accumulated into z ----------------
__global__ __launch_bounds__(1024) void gpool_k(const float* __restrict__ X,
                                                float* __restrict__ z, int k)
{
    __shared__ float smx[8][128];
    __shared__ float ssm[8][128];
    const int b = blockIdx.x;
    const int col = threadIdx.x & 127;
    const int rg = threadIdx.x >> 7;
    const float* xp = X + (size_t)b * k * 128 + col;
    float mx = -FLT_MAX, sm = 0.f;
    int r = rg;
#pragma unroll 4
    for (; r + 32 <= k; r += 32) {
        float v0 = xp[(size_t)(r + 0)  * 128];
        float v1 = xp[(size_t)(r + 8)  * 128];
        float v2 = xp[(size_t)(r + 16) * 128];
        float v3 = xp[(size_t)(r + 24) * 128];
        mx = fmaxf(fmaxf(fmaxf(mx, v0), fmaxf(v1, v2)), v3);
        sm += v0 + v1 + v2 + v3;
    }
    for (; r < k; r += 8) {
        float v = xp[(size_t)r * 128];
        mx = fmaxf(mx, v);
        sm += v;
    }
    smx[rg][col] = mx;
    ssm[rg][col] = sm;
    __syncthreads();
    if (rg == 0) {
#pragma unroll
        for (int i = 1; i < 8; i++) { mx = fmaxf(mx, smx[i][col]); sm += ssm[i][col]; }
        z[b * 256 + col] += mx;
        z[b * 256 + 128 + col] += sm / (float)k;
    }
}

extern "C" void kernel_launch(void* const* d_in, const int* in_sizes, int n_in,
                              void* d_out, int out_size, void* d_ws, size_t ws_size,
                              hipStream_t stream)
{
    (void)in_sizes; (void)n_in; (void)out_size; (void)ws_size;

    const float* x   = (const float*)d_in[0];
    const int*   ei  = (const int*)d_in[2];
    const float* W1  = (const float*)d_in[4];
    const float* as1 = (const float*)d_in[5];
    const float* ad1 = (const float*)d_in[6];
    const float* b1  = (const float*)d_in[7];
    const float* Wh1 = (const float*)d_in[8];
    const float* bh1 = (const float*)d_in[9];
    const float* pw1 = (const float*)d_in[10];
    const float* W2  = (const float*)d_in[11];
    const float* as2 = (const float*)d_in[12];
    const float* ad2 = (const float*)d_in[13];
    const float* b2  = (const float*)d_in[14];
    const float* Wh2 = (const float*)d_in[15];
    const float* bh2 = (const float*)d_in[16];
    const float* pw2 = (const float*)d_in[17];
    const float* W3  = (const float*)d_in[18];
    const float* as3 = (const float*)d_in[19];
    const float* ad3 = (const float*)d_in[20];
    const float* b3  = (const float*)d_in[21];
    const float* Wh3 = (const float*)d_in[22];
    const float* bh3 = (const float*)d_in[23];
    const float* pw3 = (const float*)d_in[24];
    const float* Wl1 = (const float*)d_in[25];
    const float* bl1 = (const float*)d_in[26];
    const float* Wl2 = (const float*)d_in[27];
    const float* bl2 = (const float*)d_in[28];
    float* out = (float*)d_out;

    const int E = 131072;
    const int n1 = 32768, per1 = 512, k1 = 410;
    const int n2 = 64 * k1, per2 = k1, k2 = 205;   // 26240, 410, 205
    const int n3 = 64 * k2, per3 = k2, k3 = 41;    // 13120, 205, 41
    const int n4 = 64 * k3;                        // 2624

    // ---- workspace carve ----
    char* wsb = (char*)d_ws;
    size_t off = 0;
    auto alloc = [&](size_t bytes) -> void* {
        void* p = wsb + off;
        off += (bytes + 255) & ~(size_t)255;
        return p;
    };
    float* A    = (float*)alloc((size_t)n1 * 384 * 4);  // h_lin, later h2
    float* Bf   = (float*)alloc((size_t)n1 * 384 * 4);  // gat output
    float* ES   = (float*)alloc((size_t)n1 * 3 * 4);
    float* ED   = (float*)alloc((size_t)n1 * 3 * 4);
    float* SC   = (float*)alloc((size_t)n1 * 4);
    int*   DEG  = (int*)alloc((size_t)(n1 + 1) * 4);
    int*   OFFS = (int*)alloc((size_t)(n1 + 1) * 4);
    int*   CUR  = (int*)alloc((size_t)n1 * 4);
    int*   CSR  = (int*)alloc((size_t)E * 4);
    int*   SRCA = (int*)alloc((size_t)E * 4);
    int*   DSTA = (int*)alloc((size_t)E * 4);
    int*   VALA = (int*)alloc((size_t)E * 4);
    int*   SRCB = (int*)alloc((size_t)E * 4);
    int*   DSTB = (int*)alloc((size_t)E * 4);
    int*   VALB = (int*)alloc((size_t)E * 4);
    float* X1   = (float*)alloc((size_t)n2 * 128 * 4);
    float* X2   = (float*)alloc((size_t)n3 * 128 * 4);
    float* X3   = (float*)alloc((size_t)n4 * 128 * 4);
    int*   PERM = (int*)alloc((size_t)n2 * 4);
    float* PSC  = (float*)alloc((size_t)n2 * 4);
    int*   NEWID= (int*)alloc((size_t)n1 * 4);
    float* WMX  = (float*)alloc((size_t)n1 * 3 * 4);
    float* WINV = (float*)alloc((size_t)n1 * 3 * 4);
    float* WSELF= (float*)alloc((size_t)n1 * 3 * 4);
    float* ALPHA= (float*)alloc((size_t)E * 3 * 4);
    float* Z    = (float*)alloc((size_t)64 * 256 * 4);
    float* ZH   = (float*)alloc((size_t)64 * 512 * 4);

    auto layer = [&](const float* xin, int n,
                     const int* src, const int* dst, const int* val,
                     const float* W, const float* as_, const float* ad_, const float* bb,
                     const float* Wh, const float* bh, const float* pw,
                     int per, int kk, float* Xn, int nNew,
                     int* srcN, int* dstN, int* valN)
    {
        gemm_mfma_k<<<dim3((n + 127) / 128, 384 / 128), 256, 0, stream>>>(xin, W, nullptr, A, n, 128, 384, 0);
        escd_k<<<(n * 3) / 4, 256, 0, stream>>>(A, as_, ad_, ES, ED, n);
        hipMemsetAsync(DEG, 0, (size_t)n * 4, stream);
        count_k<<<E / 256, 256, 0, stream>>>(dst, val, DEG, E);
        scan_k<<<1, 1024, 0, stream>>>(DEG, OFFS, CUR, n);
        scatter_k<<<E / 256, 256, 0, stream>>>(dst, val, CUR, CSR, E);
        maxden_k<<<(n + 255) / 256, 256, 0, stream>>>(ES, ED, OFFS, CSR, src, WMX, WINV, WSELF, n);
        alpha_k<<<E / 256, 256, 0, stream>>>(src, dst, val, ES, ED, WMX, WINV, ALPHA, E);
        agg2_k<<<n / 4, 256, 0, stream>>>(A, ALPHA, WSELF, OFFS, CSR, src, bb, Bf, n);
        gemm_mfma_k<<<dim3((n + 127) / 128, 1), 256, 0, stream>>>(Bf, Wh, bh, A, n, 384, 128, 1);
        score_k<<<n / 4, 256, 0, stream>>>(A, pw, SC, n);
        hipMemsetAsync(NEWID, 0xFF, (size_t)n * 4, stream);
        int P2 = 1;
        while (P2 < per) P2 <<= 1;
        select_k<<<64, P2, 0, stream>>>(SC, per, kk, PERM, PSC, NEWID);
        gate_k<<<nNew / 4, 256, 0, stream>>>(A, PERM, PSC, Xn, nNew);
        if (srcN) remap_k<<<E / 256, 256, 0, stream>>>(src, dst, val, NEWID, srcN, dstN, valN, E);
        gpool_k<<<64, 1024, 0, stream>>>(Xn, Z, kk);
    };

    hipMemsetAsync(Z, 0, (size_t)64 * 256 * 4, stream);

    layer(x,  n1, ei,   ei + E, nullptr, W1, as1, ad1, b1, Wh1, bh1, pw1, per1, k1, X1, n2, SRCA, DSTA, VALA);
    layer(X1, n2, SRCA, DSTA,   VALA,    W2, as2, ad2, b2, Wh2, bh2, pw2, per2, k2, X2, n3, SRCB, DSTB, VALB);
    layer(X2, n3, SRCB, DSTB,   VALB,    W3, as3, ad3, b3, Wh3, bh3, pw3, per3, k3, X3, n4, nullptr, nullptr, nullptr);

    gemm_small_k<<<(64 * 512 + 255) / 256, 256, 0, stream>>>(Z,  Wl1, bl1, ZH,  64, 256, 512, 1);
    gemm_small_k<<<(64 * 256 + 255) / 256, 256, 0, stream>>>(ZH, Wl2, bl2, out, 64, 512, 256, 0);
}

// Round 6
// 472.652 us; speedup vs baseline: 2.5544x; 1.2531x over previous
//
#include <hip/hip_runtime.h>
#include <cfloat>

static __device__ __forceinline__ float lrelu(float v) { return v >= 0.f ? v : 0.2f * v; }

typedef __attribute__((ext_vector_type(8))) short bf16x8;
typedef __attribute__((ext_vector_type(4))) float f32x4;

__device__ __forceinline__ unsigned short f2bf(float x) {
    unsigned u = __float_as_uint(x);
    u += 0x7FFF + ((u >> 16) & 1);          // RNE to bf16
    return (unsigned short)(u >> 16);
}
__device__ __forceinline__ float bf2f(unsigned short h) {
    return __uint_as_float(((unsigned)h) << 16);
}

// ---------------- MFMA GEMM, fp32 in/out, split-bf16 (3-term Ootomo) ----------------
// C[M,N] = A[M,K] @ B[K,N] (+bias)(+relu). Requires K%32==0, N%128==0; M guarded.
__global__ __launch_bounds__(256) void gemm_mfma_k(const float* __restrict__ A,
                                                   const float* __restrict__ B,
                                                   const float* __restrict__ bias,
                                                   float* __restrict__ C,
                                                   int M, int K, int N, int relu)
{
    __shared__ unsigned short AsH[128 * 32], AsL[128 * 32];   // [row][k] bf16
    __shared__ unsigned short BsH[128 * 32], BsL[128 * 32];   // [col][k] bf16 (transposed)
    const int tid  = threadIdx.x;
    const int lane = tid & 63;
    const int wave = tid >> 6;
    const int wr = (wave >> 1) * 64;
    const int wc = (wave & 1) * 64;
    const int row0 = blockIdx.x * 128, col0 = blockIdx.y * 128;

    f32x4 acc[4][4];
#pragma unroll
    for (int i = 0; i < 4; i++)
#pragma unroll
        for (int j = 0; j < 4; j++) acc[i][j] = (f32x4){0.f, 0.f, 0.f, 0.f};

    const int ar  = tid >> 1;
    const int afb = (tid & 1) * 4;
    const int bk  = tid & 31;
    const int bnb = (tid >> 5) * 16;

    const int l15 = lane & 15;
    const int kc  = lane >> 4;

    const bool aok = (row0 + ar) < M;

    for (int k0 = 0; k0 < K; k0 += 32) {
        float4 av[4], bv[4];
        const float* Ap = A + (size_t)(row0 + ar) * K + k0;
        const float* Bp = B + (size_t)(k0 + bk) * N + col0 + bnb;
#pragma unroll
        for (int i = 0; i < 4; i++)
            av[i] = aok ? *reinterpret_cast<const float4*>(Ap + (afb + i) * 4)
                        : make_float4(0.f, 0.f, 0.f, 0.f);
#pragma unroll
        for (int i = 0; i < 4; i++)
            bv[i] = *reinterpret_cast<const float4*>(Bp + i * 4);

        __syncthreads();

        const int asz = (ar ^ (ar >> 2)) & 3;
#pragma unroll
        for (int i = 0; i < 4; i++) {
            int f = afb + i;
            int uidx = ar * 16 + (((f >> 1) ^ asz) << 2) + (f & 1) * 2;
            float xs[4] = {av[i].x, av[i].y, av[i].z, av[i].w};
            unsigned short h[4], l[4];
#pragma unroll
            for (int j = 0; j < 4; j++) {
                h[j] = f2bf(xs[j]);
                l[j] = f2bf(xs[j] - bf2f(h[j]));
            }
            ((unsigned*)AsH)[uidx]     = (unsigned)h[0] | ((unsigned)h[1] << 16);
            ((unsigned*)AsH)[uidx + 1] = (unsigned)h[2] | ((unsigned)h[3] << 16);
            ((unsigned*)AsL)[uidx]     = (unsigned)l[0] | ((unsigned)l[1] << 16);
            ((unsigned*)AsL)[uidx + 1] = (unsigned)l[2] | ((unsigned)l[3] << 16);
        }
#pragma unroll
        for (int i = 0; i < 4; i++) {
            float xs[4] = {bv[i].x, bv[i].y, bv[i].z, bv[i].w};
#pragma unroll
            for (int j = 0; j < 4; j++) {
                int c = bnb + i * 4 + j;
                int sidx = c * 32 + ((((bk >> 3) ^ ((c ^ (c >> 2)) & 3))) << 3) + (bk & 7);
                unsigned short h = f2bf(xs[j]);
                BsH[sidx] = h;
                BsL[sidx] = f2bf(xs[j] - bf2f(h));
            }
        }
        __syncthreads();

        bf16x8 aH[4], aL[4], bH[4], bL[4];
#pragma unroll
        for (int fi = 0; fi < 4; fi++) {
            int r = wr + fi * 16 + l15;
            int sidx = r * 32 + ((kc ^ ((r ^ (r >> 2)) & 3)) << 3);
            aH[fi] = *reinterpret_cast<const bf16x8*>(&AsH[sidx]);
            aL[fi] = *reinterpret_cast<const bf16x8*>(&AsL[sidx]);
        }
#pragma unroll
        for (int fj = 0; fj < 4; fj++) {
            int c = wc + fj * 16 + l15;
            int sidx = c * 32 + ((kc ^ ((c ^ (c >> 2)) & 3)) << 3);
            bH[fj] = *reinterpret_cast<const bf16x8*>(&BsH[sidx]);
            bL[fj] = *reinterpret_cast<const bf16x8*>(&BsL[sidx]);
        }
#pragma unroll
        for (int fi = 0; fi < 4; fi++)
#pragma unroll
            for (int fj = 0; fj < 4; fj++) {
                acc[fi][fj] = __builtin_amdgcn_mfma_f32_16x16x32_bf16(aH[fi], bH[fj], acc[fi][fj], 0, 0, 0);
                acc[fi][fj] = __builtin_amdgcn_mfma_f32_16x16x32_bf16(aH[fi], bL[fj], acc[fi][fj], 0, 0, 0);
                acc[fi][fj] = __builtin_amdgcn_mfma_f32_16x16x32_bf16(aL[fi], bH[fj], acc[fi][fj], 0, 0, 0);
            }
    }

#pragma unroll
    for (int fi = 0; fi < 4; fi++) {
        int rbase = row0 + wr + fi * 16 + (lane >> 4) * 4;
#pragma unroll
        for (int q = 0; q < 4; q++) {
            int r = rbase + q;
            if (r < M) {
#pragma unroll
                for (int fj = 0; fj < 4; fj++) {
                    int c = col0 + wc + fj * 16 + l15;
                    float v = acc[fi][fj][q];
                    if (bias) v += bias[c];
                    if (relu) v = fmaxf(v, 0.f);
                    C[(size_t)r * N + c] = v;
                }
            }
        }
    }
}

// ---------------- small-M GEMM (MLP head, M=64): one thread per output ----------------
__global__ __launch_bounds__(256) void gemm_small_k(const float* __restrict__ A,
                                                    const float* __restrict__ B,
                                                    const float* __restrict__ bias,
                                                    float* __restrict__ C,
                                                    int M, int K, int N, int relu)
{
    int idx = blockIdx.x * 256 + threadIdx.x;
    if (idx >= M * N) return;
    int r = idx / N, c = idx - r * N;
    const float* ap = A + (size_t)r * K;
    const float* bp = B + c;
    float s = 0.f;
#pragma unroll 8
    for (int k = 0; k < K; k++) s += ap[k] * bp[(size_t)k * N];
    if (bias) s += bias[c];
    if (relu) s = fmaxf(s, 0.f);
    C[idx] = s;
}

// ---------------- per-(node,head) attention coefficients e_src, e_dst ----------------
__global__ __launch_bounds__(256) void escd_k(const float* __restrict__ H,
                                              const float* __restrict__ a_src,
                                              const float* __restrict__ a_dst,
                                              float* __restrict__ es, float* __restrict__ ed, int n)
{
    int wid = (int)((blockIdx.x * 256 + threadIdx.x) >> 6);
    int lane = threadIdx.x & 63;
    if (wid >= n * 3) return;
    int node = wid / 3, head = wid - node * 3;
    const float* hp = H + (size_t)node * 384 + head * 128;
    const float* aps = a_src + head * 128;
    const float* apd = a_dst + head * 128;
    float h0 = hp[lane], h1 = hp[lane + 64];
    float s = h0 * aps[lane] + h1 * aps[lane + 64];
    float d = h0 * apd[lane] + h1 * apd[lane + 64];
#pragma unroll
    for (int o = 32; o > 0; o >>= 1) { s += __shfl_down(s, o); d += __shfl_down(d, o); }
    if (lane == 0) { es[wid] = s; ed[wid] = d; }
}

// ---------------- CSR build ----------------
__global__ __launch_bounds__(256) void count_k(const int* __restrict__ dst,
                                               const int* __restrict__ valid,
                                               int* __restrict__ deg, int E)
{
    int e = blockIdx.x * 256 + threadIdx.x;
    if (e >= E) return;
    if (!valid || valid[e]) atomicAdd(&deg[dst[e]], 1);
}

// ---------------- 3-phase parallel exclusive scan of deg[0..n) ----------------
// (round-5 lesson: single-block scan_k was 75us latency-bound; 3 parallel
//  phases of a few us each replace it)
__global__ __launch_bounds__(256) void scan1_k(const int* __restrict__ deg,
                                               int* __restrict__ part, int n)
{
    __shared__ int ws[4];
    int i = blockIdx.x * 256 + threadIdx.x;
    int v = (i < n) ? deg[i] : 0;
#pragma unroll
    for (int o = 32; o > 0; o >>= 1) v += __shfl_down(v, o);
    int lane = threadIdx.x & 63, wv = threadIdx.x >> 6;
    if (lane == 0) ws[wv] = v;
    __syncthreads();
    if (threadIdx.x == 0)
        part[blockIdx.x] = ws[0] + ws[1] + ws[2] + ws[3];
}

__global__ __launch_bounds__(256) void scan2_k(int* __restrict__ part,
                                               int* __restrict__ off, int n, int nb)
{
    __shared__ int s[256];
    int t = threadIdx.x;
    int v = (t < nb) ? part[t] : 0;
    s[t] = v;
    __syncthreads();
#pragma unroll
    for (int d = 1; d < 256; d <<= 1) {
        int u = (t >= d) ? s[t - d] : 0;
        __syncthreads();
        s[t] += u;
        __syncthreads();
    }
    if (t < nb) part[t] = s[t] - v;          // exclusive
    if (t == nb - 1) off[n] = s[t];          // total
}

__global__ __launch_bounds__(256) void scan3_k(const int* __restrict__ deg,
                                               const int* __restrict__ part,
                                               int* __restrict__ off,
                                               int* __restrict__ cur, int n)
{
    __shared__ int s[256];
    int t = threadIdx.x;
    int i = blockIdx.x * 256 + t;
    int v = (i < n) ? deg[i] : 0;
    s[t] = v;
    __syncthreads();
#pragma unroll
    for (int d = 1; d < 256; d <<= 1) {
        int u = (t >= d) ? s[t - d] : 0;
        __syncthreads();
        s[t] += u;
        __syncthreads();
    }
    if (i < n) {
        int excl = s[t] - v + part[blockIdx.x];
        off[i] = excl;
        cur[i] = excl;
    }
}

__global__ __launch_bounds__(256) void scatter_k(const int* __restrict__ dst,
                                                 const int* __restrict__ valid,
                                                 int* __restrict__ cur, int* __restrict__ csr, int E)
{
    int e = blockIdx.x * 256 + threadIdx.x;
    if (e >= E) return;
    if (!valid || valid[e]) {
        int p = atomicAdd(&cur[dst[e]], 1);
        csr[p] = e;
    }
}

// ---------------- per-dst max / denominator / self-weight (one THREAD per dst) ----------------
__global__ __launch_bounds__(256) void maxden_k(const float* __restrict__ es,
                                                const float* __restrict__ ed,
                                                const int* __restrict__ roff,
                                                const int* __restrict__ csr,
                                                const int* __restrict__ srcArr,
                                                float* __restrict__ wmx,
                                                float* __restrict__ winv,
                                                float* __restrict__ wself, int n)
{
    int d = blockIdx.x * 256 + threadIdx.x;
    if (d >= n) return;
    float edv[3], selfl[3], mx[3];
#pragma unroll
    for (int h = 0; h < 3; h++) {
        edv[h] = ed[(size_t)d * 3 + h];
        selfl[h] = lrelu(es[(size_t)d * 3 + h] + edv[h]);
        mx[h] = selfl[h];
    }
    const int beg = roff[d], end = roff[d + 1];
    for (int e = beg; e < end; e++) {
        int s = srcArr[csr[e]];
#pragma unroll
        for (int h = 0; h < 3; h++) mx[h] = fmaxf(mx[h], lrelu(es[(size_t)s * 3 + h] + edv[h]));
    }
    float den[3];
#pragma unroll
    for (int h = 0; h < 3; h++) den[h] = __expf(selfl[h] - mx[h]);
    for (int e = beg; e < end; e++) {
        int s = srcArr[csr[e]];
#pragma unroll
        for (int h = 0; h < 3; h++) den[h] += __expf(lrelu(es[(size_t)s * 3 + h] + edv[h]) - mx[h]);
    }
#pragma unroll
    for (int h = 0; h < 3; h++) {
        float inv = 1.f / (den[h] + 1e-16f);
        wmx[(size_t)d * 3 + h] = mx[h];
        winv[(size_t)d * 3 + h] = inv;
        wself[(size_t)d * 3 + h] = __expf(selfl[h] - mx[h]) * inv;
    }
}

// ---------------- per-edge alpha (one thread per edge) ----------------
__global__ __launch_bounds__(256) void alpha_k(const int* __restrict__ src,
                                               const int* __restrict__ dst,
                                               const int* __restrict__ valid,
                                               const float* __restrict__ es,
                                               const float* __restrict__ ed,
                                               const float* __restrict__ wmx,
                                               const float* __restrict__ winv,
                                               float* __restrict__ alpha, int E)
{
    int e = blockIdx.x * 256 + threadIdx.x;
    if (e >= E) return;
    if (valid && !valid[e]) return;
    int s = src[e], d = dst[e];
#pragma unroll
    for (int h = 0; h < 3; h++) {
        float l = lrelu(es[(size_t)s * 3 + h] + ed[(size_t)d * 3 + h]);
        alpha[(size_t)e * 3 + h] = __expf(l - wmx[(size_t)d * 3 + h]) * winv[(size_t)d * 3 + h];
    }
}

// ---------------- alpha-weighted gather (one wave per dst, XCD-swizzled) ----------------
__global__ __launch_bounds__(256) void agg2_k(const float* __restrict__ H,
                                              const float* __restrict__ alpha,
                                              const float* __restrict__ wself,
                                              const int* __restrict__ roff,
                                              const int* __restrict__ csr,
                                              const int* __restrict__ srcArr,
                                              const float* __restrict__ bias,
                                              float* __restrict__ out, int n)
{
    int nwg = gridDim.x;
    int bid = blockIdx.x;
    int swz = (bid & 7) * (nwg >> 3) + (bid >> 3);
    int wid = swz * 4 + (int)(threadIdx.x >> 6);
    int lane = threadIdx.x & 63;
    if (wid >= n) return;
    const int d = wid;
    float wsf[3];
#pragma unroll
    for (int h = 0; h < 3; h++) wsf[h] = wself[(size_t)d * 3 + h];
    float acc[6];
    const float* hp = H + (size_t)d * 384;
#pragma unroll
    for (int j = 0; j < 6; j++) acc[j] = wsf[j >> 1] * hp[lane + 64 * j];
    const int beg = roff[d], end = roff[d + 1];
    for (int e = beg; e < end; e++) {
        int ce = csr[e];
        int s = srcArr[ce];
        float a0 = alpha[(size_t)ce * 3 + 0];
        float a1 = alpha[(size_t)ce * 3 + 1];
        float a2 = alpha[(size_t)ce * 3 + 2];
        const float* sp = H + (size_t)s * 384;
        acc[0] += a0 * sp[lane];
        acc[1] += a0 * sp[lane + 64];
        acc[2] += a1 * sp[lane + 128];
        acc[3] += a1 * sp[lane + 192];
        acc[4] += a2 * sp[lane + 256];
        acc[5] += a2 * sp[lane + 320];
    }
#pragma unroll
    for (int j = 0; j < 6; j++)
        out[(size_t)d * 384 + lane + 64 * j] = acc[j] + bias[lane + 64 * j];
}

// ---------------- TopK pooling score: tanh(x.w / ||w||)  (one wave per node) ----------------
__global__ __launch_bounds__(256) void score_k(const float* __restrict__ H,
                                               const float* __restrict__ w,
                                               float* __restrict__ sc, int n)
{
    int wid = (int)((blockIdx.x * 256 + threadIdx.x) >> 6);
    int lane = threadIdx.x & 63;
    if (wid >= n) return;
    float w0 = w[lane], w1 = w[lane + 64];
    const float* hp = H + (size_t)wid * 128;
    float s = hp[lane] * w0 + hp[lane + 64] * w1;
    float q = w0 * w0 + w1 * w1;
#pragma unroll
    for (int o = 32; o > 0; o >>= 1) { s += __shfl_down(s, o); q += __shfl_down(q, o); }
    if (lane == 0) sc[wid] = tanhf(s / sqrtf(q));
}

// ---------------- per-graph top-k selection (bitonic sort, desc score, asc idx tiebreak) ----------------
__global__ __launch_bounds__(512) void select_k(const float* __restrict__ sc,
                                                int per, int k,
                                                int* __restrict__ perm, float* __restrict__ ps,
                                                int* __restrict__ newid)
{
    __shared__ float s[512];
    __shared__ int id[512];
    const int b = blockIdx.x;
    const int t = threadIdx.x;
    const int P = blockDim.x;
    if (t < per) { s[t] = sc[(size_t)b * per + t]; id[t] = t; }
    else         { s[t] = -FLT_MAX; id[t] = per + t; }
    __syncthreads();
    for (int kk = 2; kk <= P; kk <<= 1)
        for (int j = kk >> 1; j > 0; j >>= 1) {
            int ixj = t ^ j;
            if (ixj > t) {
                float a = s[t], bq = s[ixj];
                int ia = id[t], ib = id[ixj];
                bool aBefore = (a > bq) || (a == bq && ia < ib);
                bool up = ((t & kk) == 0);
                if (up ? !aBefore : aBefore) { s[t] = bq; s[ixj] = a; id[t] = ib; id[ixj] = ia; }
            }
            __syncthreads();
        }
    if (t < k) {
        int og = b * per + id[t];
        int ng = b * k + t;
        perm[ng] = og;
        ps[ng] = s[t];
        newid[og] = ng;
    }
}

// ---------------- gated copy of kept nodes (one wave per new node) ----------------
__global__ __launch_bounds__(256) void gate_k(const float* __restrict__ H,
                                              const int* __restrict__ perm,
                                              const float* __restrict__ ps,
                                              float* __restrict__ X, int nNew)
{
    int wid = (int)((blockIdx.x * 256 + threadIdx.x) >> 6);
    int lane = threadIdx.x & 63;
    if (wid >= nNew) return;
    int o = perm[wid];
    float g = ps[wid];
    X[(size_t)wid * 128 + lane]      = H[(size_t)o * 128 + lane] * g;
    X[(size_t)wid * 128 + 64 + lane] = H[(size_t)o * 128 + 64 + lane] * g;
}

// ---------------- edge remap through pooling ----------------
__global__ __launch_bounds__(256) void remap_k(const int* __restrict__ s_old,
                                               const int* __restrict__ d_old,
                                               const int* __restrict__ v_old,
                                               const int* __restrict__ newid,
                                               int* __restrict__ s_new, int* __restrict__ d_new,
                                               int* __restrict__ v_new, int E)
{
    int e = blockIdx.x * 256 + threadIdx.x;
    if (e >= E) return;
    int v = v_old ? v_old[e] : 1;
    int ns = -1, nd = -1;
    if (v) { ns = newid[s_old[e]]; nd = newid[d_old[e]]; }
    int ok = (v && ns >= 0 && nd >= 0) ? 1 : 0;
    s_new[e] = ok ? ns : 0;
    d_new[e] = ok ? nd : 0;
    v_new[e] = ok;
}

// ---------------- global max+mean pool, accumulated into z ----------------
__global__ __launch_bounds__(1024) void gpool_k(const float* __restrict__ X,
                                                float* __restrict__ z, int k)
{
    __shared__ float smx[8][128];
    __shared__ float ssm[8][128];
    const int b = blockIdx.x;
    const int col = threadIdx.x & 127;
    const int rg = threadIdx.x >> 7;
    const float* xp = X + (size_t)b * k * 128 + col;
    float mx = -FLT_MAX, sm = 0.f;
    int r = rg;
#pragma unroll 4
    for (; r + 32 <= k; r += 32) {
        float v0 = xp[(size_t)(r + 0)  * 128];
        float v1 = xp[(size_t)(r + 8)  * 128];
        float v2 = xp[(size_t)(r + 16) * 128];
        float v3 = xp[(size_t)(r + 24) * 128];
        mx = fmaxf(fmaxf(fmaxf(mx, v0), fmaxf(v1, v2)), v3);
        sm += v0 + v1 + v2 + v3;
    }
    for (; r < k; r += 8) {
        float v = xp[(size_t)r * 128];
        mx = fmaxf(mx, v);
        sm += v;
    }
    smx[rg][col] = mx;
    ssm[rg][col] = sm;
    __syncthreads();
    if (rg == 0) {
#pragma unroll
        for (int i = 1; i < 8; i++) { mx = fmaxf(mx, smx[i][col]); sm += ssm[i][col]; }
        z[b * 256 + col] += mx;
        z[b * 256 + 128 + col] += sm / (float)k;
    }
}

extern "C" void kernel_launch(void* const* d_in, const int* in_sizes, int n_in,
                              void* d_out, int out_size, void* d_ws, size_t ws_size,
                              hipStream_t stream)
{
    (void)in_sizes; (void)n_in; (void)out_size; (void)ws_size;

    const float* x   = (const float*)d_in[0];
    const int*   ei  = (const int*)d_in[2];
    const float* W1  = (const float*)d_in[4];
    const float* as1 = (const float*)d_in[5];
    const float* ad1 = (const float*)d_in[6];
    const float* b1  = (const float*)d_in[7];
    const float* Wh1 = (const float*)d_in[8];
    const float* bh1 = (const float*)d_in[9];
    const float* pw1 = (const float*)d_in[10];
    const float* W2  = (const float*)d_in[11];
    const float* as2 = (const float*)d_in[12];
    const float* ad2 = (const float*)d_in[13];
    const float* b2  = (const float*)d_in[14];
    const float* Wh2 = (const float*)d_in[15];
    const float* bh2 = (const float*)d_in[16];
    const float* pw2 = (const float*)d_in[17];
    const float* W3  = (const float*)d_in[18];
    const float* as3 = (const float*)d_in[19];
    const float* ad3 = (const float*)d_in[20];
    const float* b3  = (const float*)d_in[21];
    const float* Wh3 = (const float*)d_in[22];
    const float* bh3 = (const float*)d_in[23];
    const float* pw3 = (const float*)d_in[24];
    const float* Wl1 = (const float*)d_in[25];
    const float* bl1 = (const float*)d_in[26];
    const float* Wl2 = (const float*)d_in[27];
    const float* bl2 = (const float*)d_in[28];
    float* out = (float*)d_out;

    const int E = 131072;
    const int n1 = 32768, per1 = 512, k1 = 410;
    const int n2 = 64 * k1, per2 = k1, k2 = 205;   // 26240, 410, 205
    const int n3 = 64 * k2, per3 = k2, k3 = 41;    // 13120, 205, 41
    const int n4 = 64 * k3;                        // 2624

    // ---- workspace carve ----
    char* wsb = (char*)d_ws;
    size_t off = 0;
    auto alloc = [&](size_t bytes) -> void* {
        void* p = wsb + off;
        off += (bytes + 255) & ~(size_t)255;
        return p;
    };
    float* A    = (float*)alloc((size_t)n1 * 384 * 4);  // h_lin, later h2
    float* Bf   = (float*)alloc((size_t)n1 * 384 * 4);  // gat output
    float* ES   = (float*)alloc((size_t)n1 * 3 * 4);
    float* ED   = (float*)alloc((size_t)n1 * 3 * 4);
    float* SC   = (float*)alloc((size_t)n1 * 4);
    int*   DEG  = (int*)alloc((size_t)(n1 + 1) * 4);
    int*   OFFS = (int*)alloc((size_t)(n1 + 1) * 4);
    int*   CUR  = (int*)alloc((size_t)n1 * 4);
    int*   PART = (int*)alloc((size_t)256 * 4);
    int*   CSR  = (int*)alloc((size_t)E * 4);
    int*   SRCA = (int*)alloc((size_t)E * 4);
    int*   DSTA = (int*)alloc((size_t)E * 4);
    int*   VALA = (int*)alloc((size_t)E * 4);
    int*   SRCB = (int*)alloc((size_t)E * 4);
    int*   DSTB = (int*)alloc((size_t)E * 4);
    int*   VALB = (int*)alloc((size_t)E * 4);
    float* X1   = (float*)alloc((size_t)n2 * 128 * 4);
    float* X2   = (float*)alloc((size_t)n3 * 128 * 4);
    float* X3   = (float*)alloc((size_t)n4 * 128 * 4);
    int*   PERM = (int*)alloc((size_t)n2 * 4);
    float* PSC  = (float*)alloc((size_t)n2 * 4);
    int*   NEWID= (int*)alloc((size_t)n1 * 4);
    float* WMX  = (float*)alloc((size_t)n1 * 3 * 4);
    float* WINV = (float*)alloc((size_t)n1 * 3 * 4);
    float* WSELF= (float*)alloc((size_t)n1 * 3 * 4);
    float* ALPHA= (float*)alloc((size_t)E * 3 * 4);
    float* Z    = (float*)alloc((size_t)64 * 256 * 4);
    float* ZH   = (float*)alloc((size_t)64 * 512 * 4);

    auto layer = [&](const float* xin, int n,
                     const int* src, const int* dst, const int* val,
                     const float* W, const float* as_, const float* ad_, const float* bb,
                     const float* Wh, const float* bh, const float* pw,
                     int per, int kk, float* Xn, int nNew,
                     int* srcN, int* dstN, int* valN)
    {
        gemm_mfma_k<<<dim3((n + 127) / 128, 384 / 128), 256, 0, stream>>>(xin, W, nullptr, A, n, 128, 384, 0);
        escd_k<<<(n * 3) / 4, 256, 0, stream>>>(A, as_, ad_, ES, ED, n);
        hipMemsetAsync(DEG, 0, (size_t)n * 4, stream);
        count_k<<<E / 256, 256, 0, stream>>>(dst, val, DEG, E);
        int nb = (n + 255) / 256;
        scan1_k<<<nb, 256, 0, stream>>>(DEG, PART, n);
        scan2_k<<<1, 256, 0, stream>>>(PART, OFFS, n, nb);
        scan3_k<<<nb, 256, 0, stream>>>(DEG, PART, OFFS, CUR, n);
        scatter_k<<<E / 256, 256, 0, stream>>>(dst, val, CUR, CSR, E);
        maxden_k<<<(n + 255) / 256, 256, 0, stream>>>(ES, ED, OFFS, CSR, src, WMX, WINV, WSELF, n);
        alpha_k<<<E / 256, 256, 0, stream>>>(src, dst, val, ES, ED, WMX, WINV, ALPHA, E);
        agg2_k<<<n / 4, 256, 0, stream>>>(A, ALPHA, WSELF, OFFS, CSR, src, bb, Bf, n);
        gemm_mfma_k<<<dim3((n + 127) / 128, 1), 256, 0, stream>>>(Bf, Wh, bh, A, n, 384, 128, 1);
        score_k<<<n / 4, 256, 0, stream>>>(A, pw, SC, n);
        hipMemsetAsync(NEWID, 0xFF, (size_t)n * 4, stream);
        int P2 = 1;
        while (P2 < per) P2 <<= 1;
        select_k<<<64, P2, 0, stream>>>(SC, per, kk, PERM, PSC, NEWID);
        gate_k<<<nNew / 4, 256, 0, stream>>>(A, PERM, PSC, Xn, nNew);
        if (srcN) remap_k<<<E / 256, 256, 0, stream>>>(src, dst, val, NEWID, srcN, dstN, valN, E);
        gpool_k<<<64, 1024, 0, stream>>>(Xn, Z, kk);
    };

    hipMemsetAsync(Z, 0, (size_t)64 * 256 * 4, stream);

    layer(x,  n1, ei,   ei + E, nullptr, W1, as1, ad1, b1, Wh1, bh1, pw1, per1, k1, X1, n2, SRCA, DSTA, VALA);
    layer(X1, n2, SRCA, DSTA,   VALA,    W2, as2, ad2, b2, Wh2, bh2, pw2, per2, k2, X2, n3, SRCB, DSTB, VALB);
    layer(X2, n3, SRCB, DSTB,   VALB,    W3, as3, ad3, b3, Wh3, bh3, pw3, per3, k3, X3, n4, nullptr, nullptr, nullptr);

    gemm_small_k<<<(64 * 512 + 255) / 256, 256, 0, stream>>>(Z,  Wl1, bl1, ZH,  64, 256, 512, 1);
    gemm_small_k<<<(64 * 256 + 255) / 256, 256, 0, stream>>>(ZH, Wl2, bl2, out, 64, 512, 256, 0);
}

// Round 7
// 436.323 us; speedup vs baseline: 2.7671x; 1.0833x over previous
//
#include <hip/hip_runtime.h>
#include <cfloat>

static __device__ __forceinline__ float lrelu(float v) { return v >= 0.f ? v : 0.2f * v; }

typedef __attribute__((ext_vector_type(8))) short bf16x8;
typedef __attribute__((ext_vector_type(8))) unsigned short ushort8;
typedef __attribute__((ext_vector_type(4))) float f32x4;

__device__ __forceinline__ unsigned short f2bf(float x) {
    unsigned u = __float_as_uint(x);
    u += 0x7FFF + ((u >> 16) & 1);          // RNE to bf16
    return (unsigned short)(u >> 16);
}
__device__ __forceinline__ float bf2f(unsigned short h) {
    return __uint_as_float(((unsigned)h) << 16);
}

// ---------------- batched fp32 -> bf16 hi/lo split (optionally transposed) ----------------
struct SegT { const float* s; unsigned short* dh; unsigned short* dl; int rows, cols, tr; };
struct Segs { SegT seg[7]; int cum[8]; };

__global__ __launch_bounds__(256) void split_k(Segs S, int total)
{
    int idx = blockIdx.x * 256 + threadIdx.x;
    if (idx >= total) return;
    int si = 0;
    while (idx >= S.cum[si + 1]) si++;
    int o = idx - S.cum[si];
    SegT g = S.seg[si];
    float v = g.s[o];
    unsigned short h = f2bf(v);
    unsigned short l = f2bf(v - bf2f(h));
    int di = o;
    if (g.tr) { int r = o / g.cols, c = o - r * g.cols; di = c * g.rows + r; }
    g.dh[di] = h;
    g.dl[di] = l;
}

// ---------------- MFMA GEMM on pre-split bf16 hi/lo (3-term Ootomo) ----------------
// C[M,N] = A[M,K] @ B[K,N] (+bias)(+relu). A as AH/AL [M][K]; B as BTH/BTL [N][K]
// (pre-transposed). Requires M%64==0, N%128==0, K%32==0.
// BM=64, BN=128, BK=32; 256 thr = 4 waves 2x2, per-wave 32x64 output.
__global__ __launch_bounds__(256) void gemm_bf2_k(const unsigned short* __restrict__ AH,
                                                  const unsigned short* __restrict__ AL,
                                                  const unsigned short* __restrict__ BTH,
                                                  const unsigned short* __restrict__ BTL,
                                                  const float* __restrict__ bias,
                                                  float* __restrict__ C,
                                                  int M, int K, int N, int relu)
{
    __shared__ unsigned short sAH[64 * 32], sAL[64 * 32];     // [row][k]
    __shared__ unsigned short sBH[128 * 32], sBL[128 * 32];   // [col][k]
    const int tid  = threadIdx.x;
    const int lane = tid & 63;
    const int wave = tid >> 6;
    const int wr = (wave >> 1) * 32;
    const int wc = (wave & 1) * 64;
    const int row0 = blockIdx.x * 64, col0 = blockIdx.y * 128;

    f32x4 acc[2][4];
#pragma unroll
    for (int i = 0; i < 2; i++)
#pragma unroll
        for (int j = 0; j < 4; j++) acc[i][j] = (f32x4){0.f, 0.f, 0.f, 0.f};

    // staging maps
    const int a_r = tid >> 2;                 // 0..63
    const int a_c = tid & 3;                  // chunk of 8
    const int a_slot = a_r * 32 + ((a_c ^ ((a_r ^ (a_r >> 2)) & 3)) << 3);
    const unsigned short* ApH = AH + (size_t)(row0 + a_r) * K + a_c * 8;
    const unsigned short* ApL = AL + (size_t)(row0 + a_r) * K + a_c * 8;

    const int b_c = tid >> 1;                 // 0..127
    const int b_h = (tid & 1) * 2;            // chunk base
    const int b_sw = (b_c ^ (b_c >> 2)) & 3;
    const unsigned short* BpH = BTH + (size_t)(col0 + b_c) * K + b_h * 8;
    const unsigned short* BpL = BTL + (size_t)(col0 + b_c) * K + b_h * 8;

    const int l15 = lane & 15;
    const int kc  = lane >> 4;

    for (int k0 = 0; k0 < K; k0 += 32) {
        ushort8 vah = *reinterpret_cast<const ushort8*>(ApH + k0);
        ushort8 val = *reinterpret_cast<const ushort8*>(ApL + k0);
        ushort8 vb[4];
        vb[0] = *reinterpret_cast<const ushort8*>(BpH + k0);
        vb[1] = *reinterpret_cast<const ushort8*>(BpH + k0 + 8);
        vb[2] = *reinterpret_cast<const ushort8*>(BpL + k0);
        vb[3] = *reinterpret_cast<const ushort8*>(BpL + k0 + 8);

        __syncthreads();   // previous iteration's LDS reads done

        *reinterpret_cast<ushort8*>(&sAH[a_slot]) = vah;
        *reinterpret_cast<ushort8*>(&sAL[a_slot]) = val;
        {
            int s0 = b_c * 32 + (((b_h + 0) ^ b_sw) << 3);
            int s1 = b_c * 32 + (((b_h + 1) ^ b_sw) << 3);
            *reinterpret_cast<ushort8*>(&sBH[s0]) = vb[0];
            *reinterpret_cast<ushort8*>(&sBH[s1]) = vb[1];
            *reinterpret_cast<ushort8*>(&sBL[s0]) = vb[2];
            *reinterpret_cast<ushort8*>(&sBL[s1]) = vb[3];
        }
        __syncthreads();

        bf16x8 aH[2], aL[2], bH[4], bL[4];
#pragma unroll
        for (int fi = 0; fi < 2; fi++) {
            int r = wr + fi * 16 + l15;
            int sidx = r * 32 + ((kc ^ ((r ^ (r >> 2)) & 3)) << 3);
            aH[fi] = *reinterpret_cast<const bf16x8*>(&sAH[sidx]);
            aL[fi] = *reinterpret_cast<const bf16x8*>(&sAL[sidx]);
        }
#pragma unroll
        for (int fj = 0; fj < 4; fj++) {
            int c = wc + fj * 16 + l15;
            int sidx = c * 32 + ((kc ^ ((c ^ (c >> 2)) & 3)) << 3);
            bH[fj] = *reinterpret_cast<const bf16x8*>(&sBH[sidx]);
            bL[fj] = *reinterpret_cast<const bf16x8*>(&sBL[sidx]);
        }
#pragma unroll
        for (int fi = 0; fi < 2; fi++)
#pragma unroll
            for (int fj = 0; fj < 4; fj++) {
                acc[fi][fj] = __builtin_amdgcn_mfma_f32_16x16x32_bf16(aH[fi], bH[fj], acc[fi][fj], 0, 0, 0);
                acc[fi][fj] = __builtin_amdgcn_mfma_f32_16x16x32_bf16(aH[fi], bL[fj], acc[fi][fj], 0, 0, 0);
                acc[fi][fj] = __builtin_amdgcn_mfma_f32_16x16x32_bf16(aL[fi], bH[fj], acc[fi][fj], 0, 0, 0);
            }
    }

    // epilogue: C/D layout col=lane&15, row=(lane>>4)*4+q
#pragma unroll
    for (int fi = 0; fi < 2; fi++) {
        int rbase = row0 + wr + fi * 16 + (lane >> 4) * 4;
#pragma unroll
        for (int q = 0; q < 4; q++) {
            int r = rbase + q;
#pragma unroll
            for (int fj = 0; fj < 4; fj++) {
                int c = col0 + wc + fj * 16 + l15;
                float v = acc[fi][fj][q];
                if (bias) v += bias[c];
                if (relu) v = fmaxf(v, 0.f);
                C[(size_t)r * N + c] = v;
            }
        }
    }
}

// ---------------- small-M GEMM (MLP head, M=64): one thread per output ----------------
__global__ __launch_bounds__(256) void gemm_small_k(const float* __restrict__ A,
                                                    const float* __restrict__ B,
                                                    const float* __restrict__ bias,
                                                    float* __restrict__ C,
                                                    int M, int K, int N, int relu)
{
    int idx = blockIdx.x * 256 + threadIdx.x;
    if (idx >= M * N) return;
    int r = idx / N, c = idx - r * N;
    const float* ap = A + (size_t)r * K;
    const float* bp = B + c;
    float s = 0.f;
#pragma unroll 8
    for (int k = 0; k < K; k++) s += ap[k] * bp[(size_t)k * N];
    if (bias) s += bias[c];
    if (relu) s = fmaxf(s, 0.f);
    C[idx] = s;
}

// ---------------- per-(node,head) attention coefficients e_src, e_dst ----------------
__global__ __launch_bounds__(256) void escd_k(const float* __restrict__ H,
                                              const float* __restrict__ a_src,
                                              const float* __restrict__ a_dst,
                                              float* __restrict__ es, float* __restrict__ ed, int n)
{
    int wid = (int)((blockIdx.x * 256 + threadIdx.x) >> 6);
    int lane = threadIdx.x & 63;
    if (wid >= n * 3) return;
    int node = wid / 3, head = wid - node * 3;
    const float* hp = H + (size_t)node * 384 + head * 128;
    const float* aps = a_src + head * 128;
    const float* apd = a_dst + head * 128;
    float h0 = hp[lane], h1 = hp[lane + 64];
    float s = h0 * aps[lane] + h1 * aps[lane + 64];
    float d = h0 * apd[lane] + h1 * apd[lane + 64];
#pragma unroll
    for (int o = 32; o > 0; o >>= 1) { s += __shfl_down(s, o); d += __shfl_down(d, o); }
    if (lane == 0) { es[wid] = s; ed[wid] = d; }
}

// ---------------- CSR build ----------------
__global__ __launch_bounds__(256) void count_k(const int* __restrict__ dst,
                                               const int* __restrict__ valid,
                                               int* __restrict__ deg, int E)
{
    int e = blockIdx.x * 256 + threadIdx.x;
    if (e >= E) return;
    if (!valid || valid[e]) atomicAdd(&deg[dst[e]], 1);
}

// ---------------- 3-phase parallel exclusive scan ----------------
__global__ __launch_bounds__(256) void scan1_k(const int* __restrict__ deg,
                                               int* __restrict__ part, int n)
{
    __shared__ int ws[4];
    int i = blockIdx.x * 256 + threadIdx.x;
    int v = (i < n) ? deg[i] : 0;
#pragma unroll
    for (int o = 32; o > 0; o >>= 1) v += __shfl_down(v, o);
    int lane = threadIdx.x & 63, wv = threadIdx.x >> 6;
    if (lane == 0) ws[wv] = v;
    __syncthreads();
    if (threadIdx.x == 0)
        part[blockIdx.x] = ws[0] + ws[1] + ws[2] + ws[3];
}

__global__ __launch_bounds__(256) void scan2_k(int* __restrict__ part,
                                               int* __restrict__ off, int n, int nb)
{
    __shared__ int s[256];
    int t = threadIdx.x;
    int v = (t < nb) ? part[t] : 0;
    s[t] = v;
    __syncthreads();
#pragma unroll
    for (int d = 1; d < 256; d <<= 1) {
        int u = (t >= d) ? s[t - d] : 0;
        __syncthreads();
        s[t] += u;
        __syncthreads();
    }
    if (t < nb) part[t] = s[t] - v;
    if (t == nb - 1) off[n] = s[t];
}

__global__ __launch_bounds__(256) void scan3_k(const int* __restrict__ deg,
                                               const int* __restrict__ part,
                                               int* __restrict__ off,
                                               int* __restrict__ cur, int n)
{
    __shared__ int s[256];
    int t = threadIdx.x;
    int i = blockIdx.x * 256 + t;
    int v = (i < n) ? deg[i] : 0;
    s[t] = v;
    __syncthreads();
#pragma unroll
    for (int d = 1; d < 256; d <<= 1) {
        int u = (t >= d) ? s[t - d] : 0;
        __syncthreads();
        s[t] += u;
        __syncthreads();
    }
    if (i < n) {
        int excl = s[t] - v + part[blockIdx.x];
        off[i] = excl;
        cur[i] = excl;
    }
}

__global__ __launch_bounds__(256) void scatter_k(const int* __restrict__ dst,
                                                 const int* __restrict__ valid,
                                                 int* __restrict__ cur, int* __restrict__ csr, int E)
{
    int e = blockIdx.x * 256 + threadIdx.x;
    if (e >= E) return;
    if (!valid || valid[e]) {
        int p = atomicAdd(&cur[dst[e]], 1);
        csr[p] = e;
    }
}

// ---------------- per-dst max / denominator / self-weight (one THREAD per dst) ----------------
__global__ __launch_bounds__(256) void maxden_k(const float* __restrict__ es,
                                                const float* __restrict__ ed,
                                                const int* __restrict__ roff,
                                                const int* __restrict__ csr,
                                                const int* __restrict__ srcArr,
                                                float* __restrict__ wmx,
                                                float* __restrict__ winv,
                                                float* __restrict__ wself, int n)
{
    int d = blockIdx.x * 256 + threadIdx.x;
    if (d >= n) return;
    float edv[3], selfl[3], mx[3];
#pragma unroll
    for (int h = 0; h < 3; h++) {
        edv[h] = ed[(size_t)d * 3 + h];
        selfl[h] = lrelu(es[(size_t)d * 3 + h] + edv[h]);
        mx[h] = selfl[h];
    }
    const int beg = roff[d], end = roff[d + 1];
    for (int e = beg; e < end; e++) {
        int s = srcArr[csr[e]];
#pragma unroll
        for (int h = 0; h < 3; h++) mx[h] = fmaxf(mx[h], lrelu(es[(size_t)s * 3 + h] + edv[h]));
    }
    float den[3];
#pragma unroll
    for (int h = 0; h < 3; h++) den[h] = __expf(selfl[h] - mx[h]);
    for (int e = beg; e < end; e++) {
        int s = srcArr[csr[e]];
#pragma unroll
        for (int h = 0; h < 3; h++) den[h] += __expf(lrelu(es[(size_t)s * 3 + h] + edv[h]) - mx[h]);
    }
#pragma unroll
    for (int h = 0; h < 3; h++) {
        float inv = 1.f / (den[h] + 1e-16f);
        wmx[(size_t)d * 3 + h] = mx[h];
        winv[(size_t)d * 3 + h] = inv;
        wself[(size_t)d * 3 + h] = __expf(selfl[h] - mx[h]) * inv;
    }
}

// ---------------- per-edge alpha (one thread per edge) ----------------
__global__ __launch_bounds__(256) void alpha_k(const int* __restrict__ src,
                                               const int* __restrict__ dst,
                                               const int* __restrict__ valid,
                                               const float* __restrict__ es,
                                               const float* __restrict__ ed,
                                               const float* __restrict__ wmx,
                                               const float* __restrict__ winv,
                                               float* __restrict__ alpha, int E)
{
    int e = blockIdx.x * 256 + threadIdx.x;
    if (e >= E) return;
    if (valid && !valid[e]) return;
    int s = src[e], d = dst[e];
#pragma unroll
    for (int h = 0; h < 3; h++) {
        float l = lrelu(es[(size_t)s * 3 + h] + ed[(size_t)d * 3 + h]);
        alpha[(size_t)e * 3 + h] = __expf(l - wmx[(size_t)d * 3 + h]) * winv[(size_t)d * 3 + h];
    }
}

// ---------------- alpha-weighted gather; emits bf16 hi/lo for the next GEMM ----------------
__global__ __launch_bounds__(256) void agg2_k(const float* __restrict__ H,
                                              const float* __restrict__ alpha,
                                              const float* __restrict__ wself,
                                              const int* __restrict__ roff,
                                              const int* __restrict__ csr,
                                              const int* __restrict__ srcArr,
                                              const float* __restrict__ bias,
                                              unsigned short* __restrict__ outH,
                                              unsigned short* __restrict__ outL, int n)
{
    int nwg = gridDim.x;
    int bid = blockIdx.x;
    int swz = (bid & 7) * (nwg >> 3) + (bid >> 3);
    int wid = swz * 4 + (int)(threadIdx.x >> 6);
    int lane = threadIdx.x & 63;
    if (wid >= n) return;
    const int d = wid;
    float wsf[3];
#pragma unroll
    for (int h = 0; h < 3; h++) wsf[h] = wself[(size_t)d * 3 + h];
    float acc[6];
    const float* hp = H + (size_t)d * 384;
#pragma unroll
    for (int j = 0; j < 6; j++) acc[j] = wsf[j >> 1] * hp[lane + 64 * j];
    const int beg = roff[d], end = roff[d + 1];
    for (int e = beg; e < end; e++) {
        int ce = csr[e];
        int s = srcArr[ce];
        float a0 = alpha[(size_t)ce * 3 + 0];
        float a1 = alpha[(size_t)ce * 3 + 1];
        float a2 = alpha[(size_t)ce * 3 + 2];
        const float* sp = H + (size_t)s * 384;
        acc[0] += a0 * sp[lane];
        acc[1] += a0 * sp[lane + 64];
        acc[2] += a1 * sp[lane + 128];
        acc[3] += a1 * sp[lane + 192];
        acc[4] += a2 * sp[lane + 256];
        acc[5] += a2 * sp[lane + 320];
    }
#pragma unroll
    for (int j = 0; j < 6; j++) {
        float v = acc[j] + bias[lane + 64 * j];
        unsigned short h = f2bf(v);
        outH[(size_t)d * 384 + lane + 64 * j] = h;
        outL[(size_t)d * 384 + lane + 64 * j] = f2bf(v - bf2f(h));
    }
}

// ---------------- TopK pooling score: tanh(x.w / ||w||)  (one wave per node) ----------------
__global__ __launch_bounds__(256) void score_k(const float* __restrict__ H,
                                               const float* __restrict__ w,
                                               float* __restrict__ sc, int n)
{
    int wid = (int)((blockIdx.x * 256 + threadIdx.x) >> 6);
    int lane = threadIdx.x & 63;
    if (wid >= n) return;
    float w0 = w[lane], w1 = w[lane + 64];
    const float* hp = H + (size_t)wid * 128;
    float s = hp[lane] * w0 + hp[lane + 64] * w1;
    float q = w0 * w0 + w1 * w1;
#pragma unroll
    for (int o = 32; o > 0; o >>= 1) { s += __shfl_down(s, o); q += __shfl_down(q, o); }
    if (lane == 0) sc[wid] = tanhf(s / sqrtf(q));
}

// ---------------- per-graph top-k selection (bitonic sort) ----------------
__global__ __launch_bounds__(512) void select_k(const float* __restrict__ sc,
                                                int per, int k,
                                                int* __restrict__ perm, float* __restrict__ ps,
                                                int* __restrict__ newid)
{
    __shared__ float s[512];
    __shared__ int id[512];
    const int b = blockIdx.x;
    const int t = threadIdx.x;
    const int P = blockDim.x;
    if (t < per) { s[t] = sc[(size_t)b * per + t]; id[t] = t; }
    else         { s[t] = -FLT_MAX; id[t] = per + t; }
    __syncthreads();
    for (int kk = 2; kk <= P; kk <<= 1)
        for (int j = kk >> 1; j > 0; j >>= 1) {
            int ixj = t ^ j;
            if (ixj > t) {
                float a = s[t], bq = s[ixj];
                int ia = id[t], ib = id[ixj];
                bool aBefore = (a > bq) || (a == bq && ia < ib);
                bool up = ((t & kk) == 0);
                if (up ? !aBefore : aBefore) { s[t] = bq; s[ixj] = a; id[t] = ib; id[ixj] = ia; }
            }
            __syncthreads();
        }
    if (t < k) {
        int og = b * per + id[t];
        int ng = b * k + t;
        perm[ng] = og;
        ps[ng] = s[t];
        newid[og] = ng;
    }
}

// ---------------- gated copy of kept nodes: fp32 (for gpool) + bf16 hi/lo (for GEMM) ----------------
__global__ __launch_bounds__(256) void gate_k(const float* __restrict__ H,
                                              const int* __restrict__ perm,
                                              const float* __restrict__ ps,
                                              float* __restrict__ X,
                                              unsigned short* __restrict__ XH,
                                              unsigned short* __restrict__ XL, int nNew)
{
    int wid = (int)((blockIdx.x * 256 + threadIdx.x) >> 6);
    int lane = threadIdx.x & 63;
    if (wid >= nNew) return;
    int o = perm[wid];
    float g = ps[wid];
    float v0 = H[(size_t)o * 128 + lane] * g;
    float v1 = H[(size_t)o * 128 + 64 + lane] * g;
    X[(size_t)wid * 128 + lane] = v0;
    X[(size_t)wid * 128 + 64 + lane] = v1;
    unsigned short h0 = f2bf(v0), h1 = f2bf(v1);
    XH[(size_t)wid * 128 + lane] = h0;
    XH[(size_t)wid * 128 + 64 + lane] = h1;
    XL[(size_t)wid * 128 + lane] = f2bf(v0 - bf2f(h0));
    XL[(size_t)wid * 128 + 64 + lane] = f2bf(v1 - bf2f(h1));
}

// ---------------- edge remap through pooling ----------------
__global__ __launch_bounds__(256) void remap_k(const int* __restrict__ s_old,
                                               const int* __restrict__ d_old,
                                               const int* __restrict__ v_old,
                                               const int* __restrict__ newid,
                                               int* __restrict__ s_new, int* __restrict__ d_new,
                                               int* __restrict__ v_new, int E)
{
    int e = blockIdx.x * 256 + threadIdx.x;
    if (e >= E) return;
    int v = v_old ? v_old[e] : 1;
    int ns = -1, nd = -1;
    if (v) { ns = newid[s_old[e]]; nd = newid[d_old[e]]; }
    int ok = (v && ns >= 0 && nd >= 0) ? 1 : 0;
    s_new[e] = ok ? ns : 0;
    d_new[e] = ok ? nd : 0;
    v_new[e] = ok;
}

// ---------------- global max+mean pool, accumulated into z ----------------
__global__ __launch_bounds__(1024) void gpool_k(const float* __restrict__ X,
                                                float* __restrict__ z, int k)
{
    __shared__ float smx[8][128];
    __shared__ float ssm[8][128];
    const int b = blockIdx.x;
    const int col = threadIdx.x & 127;
    const int rg = threadIdx.x >> 7;
    const float* xp = X + (size_t)b * k * 128 + col;
    float mx = -FLT_MAX, sm = 0.f;
    int r = rg;
#pragma unroll 4
    for (; r + 32 <= k; r += 32) {
        float v0 = xp[(size_t)(r + 0)  * 128];
        float v1 = xp[(size_t)(r + 8)  * 128];
        float v2 = xp[(size_t)(r + 16) * 128];
        float v3 = xp[(size_t)(r + 24) * 128];
        mx = fmaxf(fmaxf(fmaxf(mx, v0), fmaxf(v1, v2)), v3);
        sm += v0 + v1 + v2 + v3;
    }
    for (; r < k; r += 8) {
        float v = xp[(size_t)r * 128];
        mx = fmaxf(mx, v);
        sm += v;
    }
    smx[rg][col] = mx;
    ssm[rg][col] = sm;
    __syncthreads();
    if (rg == 0) {
#pragma unroll
        for (int i = 1; i < 8; i++) { mx = fmaxf(mx, smx[i][col]); sm += ssm[i][col]; }
        z[b * 256 + col] += mx;
        z[b * 256 + 128 + col] += sm / (float)k;
    }
}

extern "C" void kernel_launch(void* const* d_in, const int* in_sizes, int n_in,
                              void* d_out, int out_size, void* d_ws, size_t ws_size,
                              hipStream_t stream)
{
    (void)in_sizes; (void)n_in; (void)out_size; (void)ws_size;

    const float* x   = (const float*)d_in[0];
    const int*   ei  = (const int*)d_in[2];
    const float* W1  = (const float*)d_in[4];
    const float* as1 = (const float*)d_in[5];
    const float* ad1 = (const float*)d_in[6];
    const float* b1  = (const float*)d_in[7];
    const float* Wh1 = (const float*)d_in[8];
    const float* bh1 = (const float*)d_in[9];
    const float* pw1 = (const float*)d_in[10];
    const float* W2  = (const float*)d_in[11];
    const float* as2 = (const float*)d_in[12];
    const float* ad2 = (const float*)d_in[13];
    const float* b2  = (const float*)d_in[14];
    const float* Wh2 = (const float*)d_in[15];
    const float* bh2 = (const float*)d_in[16];
    const float* pw2 = (const float*)d_in[17];
    const float* W3  = (const float*)d_in[18];
    const float* as3 = (const float*)d_in[19];
    const float* ad3 = (const float*)d_in[20];
    const float* b3  = (const float*)d_in[21];
    const float* Wh3 = (const float*)d_in[22];
    const float* bh3 = (const float*)d_in[23];
    const float* pw3 = (const float*)d_in[24];
    const float* Wl1 = (const float*)d_in[25];
    const float* bl1 = (const float*)d_in[26];
    const float* Wl2 = (const float*)d_in[27];
    const float* bl2 = (const float*)d_in[28];
    float* out = (float*)d_out;

    const int E = 131072;
    const int n1 = 32768, per1 = 512, k1 = 410;
    const int n2 = 64 * k1, per2 = k1, k2 = 205;   // 26240, 410, 205
    const int n3 = 64 * k2, per3 = k2, k3 = 41;    // 13120, 205, 41
    const int n4 = 64 * k3;                        // 2624

    // ---- workspace carve ----
    char* wsb = (char*)d_ws;
    size_t off = 0;
    auto alloc = [&](size_t bytes) -> void* {
        void* p = wsb + off;
        off += (bytes + 255) & ~(size_t)255;
        return p;
    };
    float* A    = (float*)alloc((size_t)n1 * 384 * 4);        // GAT lin out / h2
    unsigned short* BfH = (unsigned short*)alloc((size_t)n1 * 384 * 2);
    unsigned short* BfL = (unsigned short*)alloc((size_t)n1 * 384 * 2);
    unsigned short* X0H = (unsigned short*)alloc((size_t)n1 * 128 * 2);
    unsigned short* X0L = (unsigned short*)alloc((size_t)n1 * 128 * 2);
    unsigned short* XaH = (unsigned short*)alloc((size_t)n2 * 128 * 2);
    unsigned short* XaL = (unsigned short*)alloc((size_t)n2 * 128 * 2);
    unsigned short* WT[6], *WTl[6];
    for (int i = 0; i < 6; i++) {
        WT[i]  = (unsigned short*)alloc((size_t)49152 * 2);
        WTl[i] = (unsigned short*)alloc((size_t)49152 * 2);
    }
    float* ES   = (float*)alloc((size_t)n1 * 3 * 4);
    float* ED   = (float*)alloc((size_t)n1 * 3 * 4);
    float* SC   = (float*)alloc((size_t)n1 * 4);
    int*   DEG  = (int*)alloc((size_t)(n1 + 1) * 4);
    int*   OFFS = (int*)alloc((size_t)(n1 + 1) * 4);
    int*   CUR  = (int*)alloc((size_t)n1 * 4);
    int*   PART = (int*)alloc((size_t)256 * 4);
    int*   CSR  = (int*)alloc((size_t)E * 4);
    int*   SRCA = (int*)alloc((size_t)E * 4);
    int*   DSTA = (int*)alloc((size_t)E * 4);
    int*   VALA = (int*)alloc((size_t)E * 4);
    int*   SRCB = (int*)alloc((size_t)E * 4);
    int*   DSTB = (int*)alloc((size_t)E * 4);
    int*   VALB = (int*)alloc((size_t)E * 4);
    float* X1   = (float*)alloc((size_t)n2 * 128 * 4);
    float* X2   = (float*)alloc((size_t)n3 * 128 * 4);
    float* X3   = (float*)alloc((size_t)n4 * 128 * 4);
    int*   PERM = (int*)alloc((size_t)n2 * 4);
    float* PSC  = (float*)alloc((size_t)n2 * 4);
    int*   NEWID= (int*)alloc((size_t)n1 * 4);
    float* WMX  = (float*)alloc((size_t)n1 * 3 * 4);
    float* WINV = (float*)alloc((size_t)n1 * 3 * 4);
    float* WSELF= (float*)alloc((size_t)n1 * 3 * 4);
    float* ALPHA= (float*)alloc((size_t)E * 3 * 4);
    float* Z    = (float*)alloc((size_t)64 * 256 * 4);
    float* ZH   = (float*)alloc((size_t)64 * 512 * 4);

    // ---- one-time operand split (x row-major; weights transposed to [N][K]) ----
    {
        Segs S;
        const float* srcs[7] = {x, W1, Wh1, W2, Wh2, W3, Wh3};
        unsigned short* dh[7] = {X0H, WT[0], WT[1], WT[2], WT[3], WT[4], WT[5]};
        unsigned short* dl[7] = {X0L, WTl[0], WTl[1], WTl[2], WTl[3], WTl[4], WTl[5]};
        int rows[7] = {n1, 128, 384, 128, 384, 128, 384};
        int cols[7] = {128, 384, 128, 384, 128, 384, 128};
        int trs[7]  = {0, 1, 1, 1, 1, 1, 1};
        int cum = 0;
        for (int i = 0; i < 7; i++) {
            S.seg[i] = SegT{srcs[i], dh[i], dl[i], rows[i], cols[i], trs[i]};
            S.cum[i] = cum;
            cum += rows[i] * cols[i];
        }
        S.cum[7] = cum;
        split_k<<<(cum + 255) / 256, 256, 0, stream>>>(S, cum);
    }

    auto layer = [&](const unsigned short* xh, const unsigned short* xl, int n,
                     const int* src, const int* dst, const int* val,
                     const unsigned short* wt, const unsigned short* wtl,
                     const float* as_, const float* ad_, const float* bb,
                     const unsigned short* wht, const unsigned short* whtl,
                     const float* bh, const float* pw,
                     int per, int kk, float* Xn,
                     unsigned short* XnH, unsigned short* XnL, int nNew,
                     int* srcN, int* dstN, int* valN)
    {
        gemm_bf2_k<<<dim3(n / 64, 3), 256, 0, stream>>>(xh, xl, wt, wtl, nullptr, A, n, 128, 384, 0);
        escd_k<<<(n * 3) / 4, 256, 0, stream>>>(A, as_, ad_, ES, ED, n);
        hipMemsetAsync(DEG, 0, (size_t)n * 4, stream);
        count_k<<<E / 256, 256, 0, stream>>>(dst, val, DEG, E);
        int nb = (n + 255) / 256;
        scan1_k<<<nb, 256, 0, stream>>>(DEG, PART, n);
        scan2_k<<<1, 256, 0, stream>>>(PART, OFFS, n, nb);
        scan3_k<<<nb, 256, 0, stream>>>(DEG, PART, OFFS, CUR, n);
        scatter_k<<<E / 256, 256, 0, stream>>>(dst, val, CUR, CSR, E);
        maxden_k<<<(n + 255) / 256, 256, 0, stream>>>(ES, ED, OFFS, CSR, src, WMX, WINV, WSELF, n);
        alpha_k<<<E / 256, 256, 0, stream>>>(src, dst, val, ES, ED, WMX, WINV, ALPHA, E);
        agg2_k<<<n / 4, 256, 0, stream>>>(A, ALPHA, WSELF, OFFS, CSR, src, bb, BfH, BfL, n);
        gemm_bf2_k<<<dim3(n / 64, 1), 256, 0, stream>>>(BfH, BfL, wht, whtl, bh, A, n, 384, 128, 1);
        score_k<<<n / 4, 256, 0, stream>>>(A, pw, SC, n);
        hipMemsetAsync(NEWID, 0xFF, (size_t)n * 4, stream);
        int P2 = 1;
        while (P2 < per) P2 <<= 1;
        select_k<<<64, P2, 0, stream>>>(SC, per, kk, PERM, PSC, NEWID);
        gate_k<<<(nNew + 3) / 4, 256, 0, stream>>>(A, PERM, PSC, Xn, XnH, XnL, nNew);
        if (srcN) remap_k<<<E / 256, 256, 0, stream>>>(src, dst, val, NEWID, srcN, dstN, valN, E);
        gpool_k<<<64, 1024, 0, stream>>>(Xn, Z, kk);
    };

    hipMemsetAsync(Z, 0, (size_t)64 * 256 * 4, stream);

    layer(X0H, X0L, n1, ei,   ei + E, nullptr, WT[0], WTl[0], as1, ad1, b1, WT[1], WTl[1], bh1, pw1,
          per1, k1, X1, XaH, XaL, n2, SRCA, DSTA, VALA);
    layer(XaH, XaL, n2, SRCA, DSTA,   VALA,    WT[2], WTl[2], as2, ad2, b2, WT[3], WTl[3], bh2, pw2,
          per2, k2, X2, XaH, XaL, n3, SRCB, DSTB, VALB);
    layer(XaH, XaL, n3, SRCB, DSTB,   VALB,    WT[4], WTl[4], as3, ad3, b3, WT[5], WTl[5], bh3, pw3,
          per3, k3, X3, XaH, XaL, n4, nullptr, nullptr, nullptr);

    gemm_small_k<<<(64 * 512 + 255) / 256, 256, 0, stream>>>(Z,  Wl1, bl1, ZH,  64, 256, 512, 1);
    gemm_small_k<<<(64 * 256 + 255) / 256, 256, 0, stream>>>(ZH, Wl2, bl2, out, 64, 512, 256, 0);
}

// Round 8
// 388.602 us; speedup vs baseline: 3.1069x; 1.1228x over previous
//
#include <hip/hip_runtime.h>
#include <cfloat>

static __device__ __forceinline__ float lrelu(float v) { return v >= 0.f ? v : 0.2f * v; }

typedef __attribute__((ext_vector_type(8))) short bf16x8;
typedef __attribute__((ext_vector_type(8))) unsigned short ushort8;
typedef __attribute__((ext_vector_type(4))) float f32x4;

__device__ __forceinline__ unsigned short f2bf(float x) {
    unsigned u = __float_as_uint(x);
    u += 0x7FFF + ((u >> 16) & 1);          // RNE to bf16
    return (unsigned short)(u >> 16);
}
__device__ __forceinline__ float bf2f(unsigned short h) {
    return __uint_as_float(((unsigned)h) << 16);
}

// ---------------- batched fp32 -> bf16 hi/lo split (optionally transposed) ----------------
struct SegT { const float* s; unsigned short* dh; unsigned short* dl; int rows, cols, tr; };
struct Segs { SegT seg[7]; int cum[8]; };

__global__ __launch_bounds__(256) void split_k(Segs S, int total)
{
    int idx = blockIdx.x * 256 + threadIdx.x;
    if (idx >= total) return;
    int si = 0;
    while (idx >= S.cum[si + 1]) si++;
    int o = idx - S.cum[si];
    SegT g = S.seg[si];
    float v = g.s[o];
    unsigned short h = f2bf(v);
    unsigned short l = f2bf(v - bf2f(h));
    int di = o;
    if (g.tr) { int r = o / g.cols, c = o - r * g.cols; di = c * g.rows + r; }
    g.dh[di] = h;
    g.dl[di] = l;
}

// ---------------- Wa precompute: wa[l][j][k] = sum_c W_l[k, (j%3)*128+c] * a[j%3][c] ----------------
// j=0..2 -> a_src heads, j=3..5 -> a_dst heads. Also rn[l] = 1/||pw_l||.
struct WaArgs { const float* W[3]; const float* as_[3]; const float* ad_[3]; const float* pw[3]; };

__global__ __launch_bounds__(256) void wa_k(WaArgs a, float* __restrict__ wab, float* __restrict__ rn)
{
    int wid = blockIdx.x * 4 + (threadIdx.x >> 6);
    int lane = threadIdx.x & 63;
    if (wid < 2304) {
        int l = wid / 768, r = wid - l * 768;
        int j = r >> 7, kk = r & 127;
        int hh = j % 3;
        const float* av = (j < 3 ? a.as_[l] : a.ad_[l]) + hh * 128;
        const float* Wp = a.W[l] + (size_t)kk * 384 + hh * 128;
        float p = Wp[lane] * av[lane] + Wp[lane + 64] * av[lane + 64];
#pragma unroll
        for (int o = 32; o > 0; o >>= 1) p += __shfl_down(p, o);
        if (lane == 0) wab[l * 768 + j * 128 + kk] = p;
    } else if (wid < 2307) {
        int l = wid - 2304;
        const float* pw = a.pw[l];
        float v0 = pw[lane], v1 = pw[lane + 64];
        float p = v0 * v0 + v1 * v1;
#pragma unroll
        for (int o = 32; o > 0; o >>= 1) p += __shfl_down(p, o);
        if (lane == 0) rn[l] = 1.f / sqrtf(p);
    }
}

// ---------------- e_src/e_dst per node: es[i,h] = x[i,:] . wa[h,:] (one wave per node) ----------------
__global__ __launch_bounds__(256) void esd_k(const float* __restrict__ X,
                                             const float* __restrict__ wab,
                                             float* __restrict__ es, float* __restrict__ ed, int n)
{
    int wid = (int)((blockIdx.x * 256 + threadIdx.x) >> 6);
    int lane = threadIdx.x & 63;
    if (wid >= n) return;
    const float* xp = X + (size_t)wid * 128;
    float x0 = xp[lane], x1 = xp[lane + 64];
    float p[6];
#pragma unroll
    for (int j = 0; j < 6; j++)
        p[j] = x0 * wab[j * 128 + lane] + x1 * wab[j * 128 + 64 + lane];
#pragma unroll
    for (int o = 32; o > 0; o >>= 1)
#pragma unroll
        for (int j = 0; j < 6; j++) p[j] += __shfl_down(p[j], o);
    if (lane == 0) {
#pragma unroll
        for (int h = 0; h < 3; h++) { es[(size_t)wid * 3 + h] = p[h]; ed[(size_t)wid * 3 + h] = p[h + 3]; }
    }
}

// ---------------- MFMA GEMM on pre-split bf16 hi/lo (3-term Ootomo) + optional fused score ----------------
// C[M,N] = A[M,K] @ B[K,N] (+bias)(+relu). A as AH/AL [M][K]; B as BTH/BTL [N][K].
// M%64==0, N%128==0, K%32==0. BM=64, BN=128, BK=32; 4 waves 2x2.
// If scv != nullptr (requires N==128, gridDim.y==1): sc[r] = tanh(dot(C_row, pwv) * rnormp[0]).
__global__ __launch_bounds__(256) void gemm_bf2_k(const unsigned short* __restrict__ AH,
                                                  const unsigned short* __restrict__ AL,
                                                  const unsigned short* __restrict__ BTH,
                                                  const unsigned short* __restrict__ BTL,
                                                  const float* __restrict__ bias,
                                                  float* __restrict__ C,
                                                  int M, int K, int N, int relu,
                                                  const float* __restrict__ pwv,
                                                  const float* __restrict__ rnormp,
                                                  float* __restrict__ scv)
{
    __shared__ unsigned short sAH[64 * 32], sAL[64 * 32];     // [row][k]
    __shared__ unsigned short sBH[128 * 32], sBL[128 * 32];   // [col][k]
    __shared__ float sred[2][64];
    const int tid  = threadIdx.x;
    const int lane = tid & 63;
    const int wave = tid >> 6;
    const int wr = (wave >> 1) * 32;
    const int wc = (wave & 1) * 64;
    const int row0 = blockIdx.x * 64, col0 = blockIdx.y * 128;

    f32x4 acc[2][4];
#pragma unroll
    for (int i = 0; i < 2; i++)
#pragma unroll
        for (int j = 0; j < 4; j++) acc[i][j] = (f32x4){0.f, 0.f, 0.f, 0.f};

    const int a_r = tid >> 2;
    const int a_c = tid & 3;
    const int a_slot = a_r * 32 + ((a_c ^ ((a_r ^ (a_r >> 2)) & 3)) << 3);
    const unsigned short* ApH = AH + (size_t)(row0 + a_r) * K + a_c * 8;
    const unsigned short* ApL = AL + (size_t)(row0 + a_r) * K + a_c * 8;

    const int b_c = tid >> 1;
    const int b_h = (tid & 1) * 2;
    const int b_sw = (b_c ^ (b_c >> 2)) & 3;
    const unsigned short* BpH = BTH + (size_t)(col0 + b_c) * K + b_h * 8;
    const unsigned short* BpL = BTL + (size_t)(col0 + b_c) * K + b_h * 8;

    const int l15 = lane & 15;
    const int kc  = lane >> 4;

    for (int k0 = 0; k0 < K; k0 += 32) {
        ushort8 vah = *reinterpret_cast<const ushort8*>(ApH + k0);
        ushort8 val = *reinterpret_cast<const ushort8*>(ApL + k0);
        ushort8 vb[4];
        vb[0] = *reinterpret_cast<const ushort8*>(BpH + k0);
        vb[1] = *reinterpret_cast<const ushort8*>(BpH + k0 + 8);
        vb[2] = *reinterpret_cast<const ushort8*>(BpL + k0);
        vb[3] = *reinterpret_cast<const ushort8*>(BpL + k0 + 8);

        __syncthreads();

        *reinterpret_cast<ushort8*>(&sAH[a_slot]) = vah;
        *reinterpret_cast<ushort8*>(&sAL[a_slot]) = val;
        {
            int s0 = b_c * 32 + (((b_h + 0) ^ b_sw) << 3);
            int s1 = b_c * 32 + (((b_h + 1) ^ b_sw) << 3);
            *reinterpret_cast<ushort8*>(&sBH[s0]) = vb[0];
            *reinterpret_cast<ushort8*>(&sBH[s1]) = vb[1];
            *reinterpret_cast<ushort8*>(&sBL[s0]) = vb[2];
            *reinterpret_cast<ushort8*>(&sBL[s1]) = vb[3];
        }
        __syncthreads();

        bf16x8 aH[2], aL[2], bH[4], bL[4];
#pragma unroll
        for (int fi = 0; fi < 2; fi++) {
            int r = wr + fi * 16 + l15;
            int sidx = r * 32 + ((kc ^ ((r ^ (r >> 2)) & 3)) << 3);
            aH[fi] = *reinterpret_cast<const bf16x8*>(&sAH[sidx]);
            aL[fi] = *reinterpret_cast<const bf16x8*>(&sAL[sidx]);
        }
#pragma unroll
        for (int fj = 0; fj < 4; fj++) {
            int c = wc + fj * 16 + l15;
            int sidx = c * 32 + ((kc ^ ((c ^ (c >> 2)) & 3)) << 3);
            bH[fj] = *reinterpret_cast<const bf16x8*>(&sBH[sidx]);
            bL[fj] = *reinterpret_cast<const bf16x8*>(&sBL[sidx]);
        }
#pragma unroll
        for (int fi = 0; fi < 2; fi++)
#pragma unroll
            for (int fj = 0; fj < 4; fj++) {
                acc[fi][fj] = __builtin_amdgcn_mfma_f32_16x16x32_bf16(aH[fi], bH[fj], acc[fi][fj], 0, 0, 0);
                acc[fi][fj] = __builtin_amdgcn_mfma_f32_16x16x32_bf16(aH[fi], bL[fj], acc[fi][fj], 0, 0, 0);
                acc[fi][fj] = __builtin_amdgcn_mfma_f32_16x16x32_bf16(aL[fi], bH[fj], acc[fi][fj], 0, 0, 0);
            }
    }

    // epilogue: C/D layout col=lane&15, row=(lane>>4)*4+q; optional fused score dot
    float pwl[4];
    if (scv) {
#pragma unroll
        for (int fj = 0; fj < 4; fj++) pwl[fj] = pwv[wc + fj * 16 + l15];
    }
    float pd[2][4] = {{0.f,0.f,0.f,0.f},{0.f,0.f,0.f,0.f}};
#pragma unroll
    for (int fi = 0; fi < 2; fi++) {
        int rbase = row0 + wr + fi * 16 + (lane >> 4) * 4;
#pragma unroll
        for (int q = 0; q < 4; q++) {
            int r = rbase + q;
#pragma unroll
            for (int fj = 0; fj < 4; fj++) {
                int c = col0 + wc + fj * 16 + l15;
                float v = acc[fi][fj][q];
                if (bias) v += bias[c];
                if (relu) v = fmaxf(v, 0.f);
                C[(size_t)r * N + c] = v;
                if (scv) pd[fi][q] += v * pwl[fj];
            }
        }
    }
    if (scv) {
        float rn0 = rnormp[0];
#pragma unroll
        for (int fi = 0; fi < 2; fi++)
#pragma unroll
            for (int q = 0; q < 4; q++) {
                float s = pd[fi][q];
                s += __shfl_xor(s, 1);
                s += __shfl_xor(s, 2);
                s += __shfl_xor(s, 4);
                s += __shfl_xor(s, 8);
                if (l15 == 0) sred[wc >> 6][wr + fi * 16 + (lane >> 4) * 4 + q] = s;
            }
        __syncthreads();
        if (tid < 64)
            scv[row0 + tid] = tanhf((sred[0][tid] + sred[1][tid]) * rn0);
    }
}

// ---------------- small-M GEMM (MLP head, M=64) ----------------
__global__ __launch_bounds__(256) void gemm_small_k(const float* __restrict__ A,
                                                    const float* __restrict__ B,
                                                    const float* __restrict__ bias,
                                                    float* __restrict__ C,
                                                    int M, int K, int N, int relu)
{
    int idx = blockIdx.x * 256 + threadIdx.x;
    if (idx >= M * N) return;
    int r = idx / N, c = idx - r * N;
    const float* ap = A + (size_t)r * K;
    const float* bp = B + c;
    float s = 0.f;
#pragma unroll 8
    for (int k = 0; k < K; k++) s += ap[k] * bp[(size_t)k * N];
    if (bias) s += bias[c];
    if (relu) s = fmaxf(s, 0.f);
    C[idx] = s;
}

// ---------------- per-graph CSR build + softmax max/den (one block per graph) ----------------
// Edges of graph g occupy [g*2048,(g+1)*2048); valid dst/src node ids in [g*per,(g+1)*per).
__global__ __launch_bounds__(256) void csr_k(const int* __restrict__ src,
                                             const int* __restrict__ dst,
                                             const int* __restrict__ valid,
                                             const float* __restrict__ es,
                                             const float* __restrict__ ed,
                                             int* __restrict__ csr,
                                             int* __restrict__ beg,
                                             int* __restrict__ end,
                                             float* __restrict__ wmx,
                                             float* __restrict__ winv,
                                             float* __restrict__ wself,
                                             int per)
{
    __shared__ int sdeg[512];
    __shared__ int soff[512];
    __shared__ float ses[1536];
    __shared__ float sed[1536];
    const int g = blockIdx.x;
    const int t = threadIdx.x;
    const int bn = g * per;
    const int be = g * 2048;
    for (int i = t; i < 512; i += 256) sdeg[i] = 0;
    for (int i = t; i < per * 3; i += 256) {
        ses[i] = es[(size_t)bn * 3 + i];
        sed[i] = ed[(size_t)bn * 3 + i];
    }
    __syncthreads();
#pragma unroll
    for (int j = 0; j < 8; j++) {
        int e = be + j * 256 + t;
        if (!valid || valid[e]) atomicAdd(&sdeg[dst[e] - bn], 1);
    }
    __syncthreads();
    // inclusive scan of sdeg -> soff (512 entries, 2 per thread)
    const int i0 = t, i1 = t + 256;
    soff[i0] = sdeg[i0]; soff[i1] = sdeg[i1];
    __syncthreads();
    for (int d = 1; d < 512; d <<= 1) {
        int a0 = (i0 >= d) ? soff[i0 - d] : 0;
        int a1 = (i1 >= d) ? soff[i1 - d] : 0;
        __syncthreads();
        soff[i0] += a0; soff[i1] += a1;
        __syncthreads();
    }
    int excl0 = 0, excl1 = 0;
    if (i0 < per) { int dg = sdeg[i0]; excl0 = soff[i0] - dg; beg[bn + i0] = be + excl0; end[bn + i0] = be + excl0 + dg; }
    if (i1 < per) { int dg = sdeg[i1]; excl1 = soff[i1] - dg; beg[bn + i1] = be + excl1; end[bn + i1] = be + excl1 + dg; }
    __syncthreads();
    if (i0 < per) { soff[i0] = excl0; sdeg[i0] = excl0; }
    if (i1 < per) { soff[i1] = excl1; sdeg[i1] = excl1; }
    __syncthreads();
#pragma unroll
    for (int j = 0; j < 8; j++) {
        int e = be + j * 256 + t;
        if (!valid || valid[e]) {
            int p = atomicAdd(&sdeg[dst[e] - bn], 1);
            csr[be + p] = e;
        }
    }
    __syncthreads();
    // per-dst online softmax max/denominator (self-loop included)
    for (int i = t; i < per; i += 256) {
        float edv[3], m[3], den[3], selfl[3];
#pragma unroll
        for (int h = 0; h < 3; h++) {
            edv[h] = sed[i * 3 + h];
            selfl[h] = lrelu(ses[i * 3 + h] + edv[h]);
            m[h] = selfl[h];
            den[h] = 1.f;
        }
        const int pb = soff[i], pe = sdeg[i];
        for (int p = pb; p < pe; p++) {
            int e = csr[be + p];
            int sl = src[e] - bn;
#pragma unroll
            for (int h = 0; h < 3; h++) {
                float l = lrelu(ses[sl * 3 + h] + edv[h]);
                if (l <= m[h]) den[h] += __expf(l - m[h]);
                else { den[h] = den[h] * __expf(m[h] - l) + 1.f; m[h] = l; }
            }
        }
#pragma unroll
        for (int h = 0; h < 3; h++) {
            float inv = 1.f / (den[h] + 1e-16f);
            wmx[(size_t)(bn + i) * 3 + h] = m[h];
            winv[(size_t)(bn + i) * 3 + h] = inv;
            wself[(size_t)(bn + i) * 3 + h] = __expf(selfl[h] - m[h]) * inv;
        }
    }
}

// ---------------- alpha+gather fused: one wave per dst, XCD-swizzled; emits bf16 hi/lo ----------------
__global__ __launch_bounds__(256) void agg2_k(const float* __restrict__ H,
                                              const float* __restrict__ es,
                                              const float* __restrict__ ed,
                                              const float* __restrict__ wmx,
                                              const float* __restrict__ winv,
                                              const float* __restrict__ wself,
                                              const int* __restrict__ beg,
                                              const int* __restrict__ end,
                                              const int* __restrict__ csr,
                                              const int* __restrict__ srcArr,
                                              const float* __restrict__ bias,
                                              unsigned short* __restrict__ outH,
                                              unsigned short* __restrict__ outL, int n)
{
    int nwg = gridDim.x;
    int bid = blockIdx.x;
    int swz = (bid & 7) * (nwg >> 3) + (bid >> 3);
    int wid = swz * 4 + (int)(threadIdx.x >> 6);
    int lane = threadIdx.x & 63;
    if (wid >= n) return;
    const int d = wid;
    float edv[3], mxv[3], ivv[3], wsf[3];
#pragma unroll
    for (int h = 0; h < 3; h++) {
        edv[h] = ed[(size_t)d * 3 + h];
        mxv[h] = wmx[(size_t)d * 3 + h];
        ivv[h] = winv[(size_t)d * 3 + h];
        wsf[h] = wself[(size_t)d * 3 + h];
    }
    float acc[6];
    const float* hp = H + (size_t)d * 384;
#pragma unroll
    for (int j = 0; j < 6; j++) acc[j] = wsf[j >> 1] * hp[lane + 64 * j];
    const int pb = beg[d], pe = end[d];
    for (int p = pb; p < pe; p++) {
        int eg = csr[p];
        int s = srcArr[eg];
        float w[3];
#pragma unroll
        for (int h = 0; h < 3; h++) {
            float l = lrelu(es[(size_t)s * 3 + h] + edv[h]);
            w[h] = __expf(l - mxv[h]) * ivv[h];
        }
        const float* sp = H + (size_t)s * 384;
        acc[0] += w[0] * sp[lane];
        acc[1] += w[0] * sp[lane + 64];
        acc[2] += w[1] * sp[lane + 128];
        acc[3] += w[1] * sp[lane + 192];
        acc[4] += w[2] * sp[lane + 256];
        acc[5] += w[2] * sp[lane + 320];
    }
#pragma unroll
    for (int j = 0; j < 6; j++) {
        float v = acc[j] + bias[lane + 64 * j];
        unsigned short h = f2bf(v);
        outH[(size_t)d * 384 + lane + 64 * j] = h;
        outL[(size_t)d * 384 + lane + 64 * j] = f2bf(v - bf2f(h));
    }
}

// ---------------- per-graph top-k selection (bitonic); also writes newid=-1 for dropped ----------------
__global__ __launch_bounds__(512) void select_k(const float* __restrict__ sc,
                                                int per, int k,
                                                int* __restrict__ perm, float* __restrict__ ps,
                                                int* __restrict__ newid)
{
    __shared__ float s[512];
    __shared__ int id[512];
    const int b = blockIdx.x;
    const int t = threadIdx.x;
    const int P = blockDim.x;
    if (t < per) { s[t] = sc[(size_t)b * per + t]; id[t] = t; }
    else         { s[t] = -FLT_MAX; id[t] = per + t; }
    __syncthreads();
    for (int kk = 2; kk <= P; kk <<= 1)
        for (int j = kk >> 1; j > 0; j >>= 1) {
            int ixj = t ^ j;
            if (ixj > t) {
                float a = s[t], bq = s[ixj];
                int ia = id[t], ib = id[ixj];
                bool aBefore = (a > bq) || (a == bq && ia < ib);
                bool up = ((t & kk) == 0);
                if (up ? !aBefore : aBefore) { s[t] = bq; s[ixj] = a; id[t] = ib; id[ixj] = ia; }
            }
            __syncthreads();
        }
    if (t < k) {
        int og = b * per + id[t];
        int ng = b * k + t;
        perm[ng] = og;
        ps[ng] = s[t];
        newid[og] = ng;
    } else if (t < per) {
        newid[b * per + id[t]] = -1;
    }
}

// ---------------- gated copy of kept nodes: fp32 + bf16 hi/lo ----------------
__global__ __launch_bounds__(256) void gate_k(const float* __restrict__ H,
                                              const int* __restrict__ perm,
                                              const float* __restrict__ ps,
                                              float* __restrict__ X,
                                              unsigned short* __restrict__ XH,
                                              unsigned short* __restrict__ XL, int nNew)
{
    int wid = (int)((blockIdx.x * 256 + threadIdx.x) >> 6);
    int lane = threadIdx.x & 63;
    if (wid >= nNew) return;
    int o = perm[wid];
    float g = ps[wid];
    float v0 = H[(size_t)o * 128 + lane] * g;
    float v1 = H[(size_t)o * 128 + 64 + lane] * g;
    X[(size_t)wid * 128 + lane] = v0;
    X[(size_t)wid * 128 + 64 + lane] = v1;
    unsigned short h0 = f2bf(v0), h1 = f2bf(v1);
    XH[(size_t)wid * 128 + lane] = h0;
    XH[(size_t)wid * 128 + 64 + lane] = h1;
    XL[(size_t)wid * 128 + lane] = f2bf(v0 - bf2f(h0));
    XL[(size_t)wid * 128 + 64 + lane] = f2bf(v1 - bf2f(h1));
}

// ---------------- edge remap through pooling ----------------
__global__ __launch_bounds__(256) void remap_k(const int* __restrict__ s_old,
                                               const int* __restrict__ d_old,
                                               const int* __restrict__ v_old,
                                               const int* __restrict__ newid,
                                               int* __restrict__ s_new, int* __restrict__ d_new,
                                               int* __restrict__ v_new, int E)
{
    int e = blockIdx.x * 256 + threadIdx.x;
    if (e >= E) return;
    int v = v_old ? v_old[e] : 1;
    int ns = -1, nd = -1;
    if (v) { ns = newid[s_old[e]]; nd = newid[d_old[e]]; }
    int ok = (v && ns >= 0 && nd >= 0) ? 1 : 0;
    s_new[e] = ok ? ns : 0;
    d_new[e] = ok ? nd : 0;
    v_new[e] = ok;
}

// ---------------- global max+mean pool; first layer stores, later layers accumulate ----------------
__global__ __launch_bounds__(1024) void gpool_k(const float* __restrict__ X,
                                                float* __restrict__ z, int k, int first)
{
    __shared__ float smx[8][128];
    __shared__ float ssm[8][128];
    const int b = blockIdx.x;
    const int col = threadIdx.x & 127;
    const int rg = threadIdx.x >> 7;
    const float* xp = X + (size_t)b * k * 128 + col;
    float mx = -FLT_MAX, sm = 0.f;
    int r = rg;
#pragma unroll 4
    for (; r + 32 <= k; r += 32) {
        float v0 = xp[(size_t)(r + 0)  * 128];
        float v1 = xp[(size_t)(r + 8)  * 128];
        float v2 = xp[(size_t)(r + 16) * 128];
        float v3 = xp[(size_t)(r + 24) * 128];
        mx = fmaxf(fmaxf(fmaxf(mx, v0), fmaxf(v1, v2)), v3);
        sm += v0 + v1 + v2 + v3;
    }
    for (; r < k; r += 8) {
        float v = xp[(size_t)r * 128];
        mx = fmaxf(mx, v);
        sm += v;
    }
    smx[rg][col] = mx;
    ssm[rg][col] = sm;
    __syncthreads();
    if (rg == 0) {
#pragma unroll
        for (int i = 1; i < 8; i++) { mx = fmaxf(mx, smx[i][col]); sm += ssm[i][col]; }
        if (first) {
            z[b * 256 + col] = mx;
            z[b * 256 + 128 + col] = sm / (float)k;
        } else {
            z[b * 256 + col] += mx;
            z[b * 256 + 128 + col] += sm / (float)k;
        }
    }
}

extern "C" void kernel_launch(void* const* d_in, const int* in_sizes, int n_in,
                              void* d_out, int out_size, void* d_ws, size_t ws_size,
                              hipStream_t stream)
{
    (void)in_sizes; (void)n_in; (void)out_size; (void)ws_size;

    const float* x   = (const float*)d_in[0];
    const int*   ei  = (const int*)d_in[2];
    const float* W1  = (const float*)d_in[4];
    const float* as1 = (const float*)d_in[5];
    const float* ad1 = (const float*)d_in[6];
    const float* b1  = (const float*)d_in[7];
    const float* Wh1 = (const float*)d_in[8];
    const float* bh1 = (const float*)d_in[9];
    const float* pw1 = (const float*)d_in[10];
    const float* W2  = (const float*)d_in[11];
    const float* as2 = (const float*)d_in[12];
    const float* ad2 = (const float*)d_in[13];
    const float* b2  = (const float*)d_in[14];
    const float* Wh2 = (const float*)d_in[15];
    const float* bh2 = (const float*)d_in[16];
    const float* pw2 = (const float*)d_in[17];
    const float* W3  = (const float*)d_in[18];
    const float* as3 = (const float*)d_in[19];
    const float* ad3 = (const float*)d_in[20];
    const float* b3  = (const float*)d_in[21];
    const float* Wh3 = (const float*)d_in[22];
    const float* bh3 = (const float*)d_in[23];
    const float* pw3 = (const float*)d_in[24];
    const float* Wl1 = (const float*)d_in[25];
    const float* bl1 = (const float*)d_in[26];
    const float* Wl2 = (const float*)d_in[27];
    const float* bl2 = (const float*)d_in[28];
    float* out = (float*)d_out;

    const int E = 131072;
    const int n1 = 32768, per1 = 512, k1 = 410;
    const int n2 = 64 * k1, per2 = k1, k2 = 205;   // 26240, 410, 205
    const int n3 = 64 * k2, per3 = k2, k3 = 41;    // 13120, 205, 41
    const int n4 = 64 * k3;                        // 2624

    // ---- workspace carve ----
    char* wsb = (char*)d_ws;
    size_t off = 0;
    auto alloc = [&](size_t bytes) -> void* {
        void* p = wsb + off;
        off += (bytes + 255) & ~(size_t)255;
        return p;
    };
    float* A    = (float*)alloc((size_t)n1 * 384 * 4);
    unsigned short* BfH = (unsigned short*)alloc((size_t)n1 * 384 * 2);
    unsigned short* BfL = (unsigned short*)alloc((size_t)n1 * 384 * 2);
    unsigned short* X0H = (unsigned short*)alloc((size_t)n1 * 128 * 2);
    unsigned short* X0L = (unsigned short*)alloc((size_t)n1 * 128 * 2);
    unsigned short* XaH = (unsigned short*)alloc((size_t)n2 * 128 * 2);
    unsigned short* XaL = (unsigned short*)alloc((size_t)n2 * 128 * 2);
    unsigned short* WT[6], *WTl[6];
    for (int i = 0; i < 6; i++) {
        WT[i]  = (unsigned short*)alloc((size_t)49152 * 2);
        WTl[i] = (unsigned short*)alloc((size_t)49152 * 2);
    }
    float* ES   = (float*)alloc((size_t)n1 * 3 * 4);
    float* ED   = (float*)alloc((size_t)n1 * 3 * 4);
    float* SC   = (float*)alloc((size_t)n1 * 4);
    int*   CSR  = (int*)alloc((size_t)E * 4);
    int*   BEG  = (int*)alloc((size_t)n1 * 4);
    int*   END  = (int*)alloc((size_t)n1 * 4);
    int*   SRCA = (int*)alloc((size_t)E * 4);
    int*   DSTA = (int*)alloc((size_t)E * 4);
    int*   VALA = (int*)alloc((size_t)E * 4);
    int*   SRCB = (int*)alloc((size_t)E * 4);
    int*   DSTB = (int*)alloc((size_t)E * 4);
    int*   VALB = (int*)alloc((size_t)E * 4);
    float* X1   = (float*)alloc((size_t)n2 * 128 * 4);
    float* X2   = (float*)alloc((size_t)n3 * 128 * 4);
    float* X3   = (float*)alloc((size_t)n4 * 128 * 4);
    int*   PERM = (int*)alloc((size_t)n2 * 4);
    float* PSC  = (float*)alloc((size_t)n2 * 4);
    int*   NEWID= (int*)alloc((size_t)n1 * 4);
    float* WMX  = (float*)alloc((size_t)n1 * 3 * 4);
    float* WINV = (float*)alloc((size_t)n1 * 3 * 4);
    float* WSELF= (float*)alloc((size_t)n1 * 3 * 4);
    float* WAB  = (float*)alloc((size_t)2304 * 4);
    float* RN   = (float*)alloc((size_t)4 * 4);
    float* Z    = (float*)alloc((size_t)64 * 256 * 4);
    float* ZH   = (float*)alloc((size_t)64 * 512 * 4);

    // ---- upfront: operand split + Wa/Wd + 1/||pw|| precompute (2 launches) ----
    {
        Segs S;
        const float* srcs[7] = {x, W1, Wh1, W2, Wh2, W3, Wh3};
        unsigned short* dh[7] = {X0H, WT[0], WT[1], WT[2], WT[3], WT[4], WT[5]};
        unsigned short* dl[7] = {X0L, WTl[0], WTl[1], WTl[2], WTl[3], WTl[4], WTl[5]};
        int rows[7] = {n1, 128, 384, 128, 384, 128, 384};
        int cols[7] = {128, 384, 128, 384, 128, 384, 128};
        int trs[7]  = {0, 1, 1, 1, 1, 1, 1};
        int cum = 0;
        for (int i = 0; i < 7; i++) {
            S.seg[i] = SegT{srcs[i], dh[i], dl[i], rows[i], cols[i], trs[i]};
            S.cum[i] = cum;
            cum += rows[i] * cols[i];
        }
        S.cum[7] = cum;
        split_k<<<(cum + 255) / 256, 256, 0, stream>>>(S, cum);

        WaArgs wa;
        wa.W[0] = W1;  wa.W[1] = W2;  wa.W[2] = W3;
        wa.as_[0] = as1; wa.as_[1] = as2; wa.as_[2] = as3;
        wa.ad_[0] = ad1; wa.ad_[1] = ad2; wa.ad_[2] = ad3;
        wa.pw[0] = pw1; wa.pw[1] = pw2; wa.pw[2] = pw3;
        wa_k<<<(2307 + 3) / 4, 256, 0, stream>>>(wa, WAB, RN);
    }

    auto layer = [&](const float* Xf, const unsigned short* xh, const unsigned short* xl,
                     int n, int per, int kk, int lidx,
                     const int* src, const int* dst, const int* val,
                     const unsigned short* wt, const unsigned short* wtl, const float* bb,
                     const unsigned short* wht, const unsigned short* whtl, const float* bh,
                     const float* pw,
                     float* Xn, unsigned short* XnH, unsigned short* XnL, int nNew,
                     int* srcN, int* dstN, int* valN)
    {
        esd_k<<<n / 4, 256, 0, stream>>>(Xf, WAB + lidx * 768, ES, ED, n);
        gemm_bf2_k<<<dim3(n / 64, 3), 256, 0, stream>>>(xh, xl, wt, wtl, nullptr, A, n, 128, 384, 0,
                                                        nullptr, nullptr, nullptr);
        csr_k<<<64, 256, 0, stream>>>(src, dst, val, ES, ED, CSR, BEG, END, WMX, WINV, WSELF, per);
        agg2_k<<<n / 4, 256, 0, stream>>>(A, ES, ED, WMX, WINV, WSELF, BEG, END, CSR, src, bb, BfH, BfL, n);
        gemm_bf2_k<<<dim3(n / 64, 1), 256, 0, stream>>>(BfH, BfL, wht, whtl, bh, A, n, 384, 128, 1,
                                                        pw, RN + lidx, SC);
        int P2 = 1;
        while (P2 < per) P2 <<= 1;
        select_k<<<64, P2, 0, stream>>>(SC, per, kk, PERM, PSC, NEWID);
        gate_k<<<nNew / 4, 256, 0, stream>>>(A, PERM, PSC, Xn, XnH, XnL, nNew);
        if (srcN) remap_k<<<E / 256, 256, 0, stream>>>(src, dst, val, NEWID, srcN, dstN, valN, E);
        gpool_k<<<64, 1024, 0, stream>>>(Xn, Z, kk, lidx == 0 ? 1 : 0);
    };

    layer(x,  X0H, X0L, n1, per1, k1, 0, ei,   ei + E, nullptr,
          WT[0], WTl[0], b1, WT[1], WTl[1], bh1, pw1,
          X1, XaH, XaL, n2, SRCA, DSTA, VALA);
    layer(X1, XaH, XaL, n2, per2, k2, 1, SRCA, DSTA, VALA,
          WT[2], WTl[2], b2, WT[3], WTl[3], bh2, pw2,
          X2, XaH, XaL, n3, SRCB, DSTB, VALB);
    layer(X2, XaH, XaL, n3, per3, k3, 2, SRCB, DSTB, VALB,
          WT[4], WTl[4], b3, WT[5], WTl[5], bh3, pw3,
          X3, XaH, XaL, n4, nullptr, nullptr, nullptr);

    gemm_small_k<<<(64 * 512 + 255) / 256, 256, 0, stream>>>(Z,  Wl1, bl1, ZH,  64, 256, 512, 1);
    gemm_small_k<<<(64 * 256 + 255) / 256, 256, 0, stream>>>(ZH, Wl2, bl2, out, 64, 512, 256, 0);
}